// Round 1
// baseline (840.091 us; speedup 1.0000x reference)
//
#include <hip/hip_runtime.h>
#include <hip/hip_bf16.h>

// Problem constants (shapes are fixed by the reference; N,E read from in_sizes)
// N=50000 nodes, E=200000 directed edges, H=4 heads, D=64, NODE_IN=6, EDGE_IN=4

__device__ __forceinline__ float wave_reduce_sum(float p) {
  #pragma unroll
  for (int o = 32; o; o >>= 1) p += __shfl_xor(p, o);
  return p;
}

// ---------------- node encoder: node0 = relu(relu(x@W1+b1)@W2+b2) ----------
__global__ __launch_bounds__(256) void node_encoder(
    const float* __restrict__ x, const float* __restrict__ w1,
    const float* __restrict__ b1, const float* __restrict__ w2,
    const float* __restrict__ b2, float* __restrict__ out, int N)
{
  __shared__ float sW2[64 * 64];
  __shared__ float sH[4][64];
  int tid = threadIdx.x;
  for (int i = tid; i < 64 * 64; i += 256) sW2[i] = w2[i];
  int wave = tid >> 6, lane = tid & 63;
  int n = blockIdx.x * 4 + wave;
  int nc = n < N ? n : (N - 1);
  float h = b1[lane];
  #pragma unroll
  for (int i = 0; i < 6; ++i) h += x[nc * 6 + i] * w1[i * 64 + lane];
  h = fmaxf(h, 0.f);
  sH[wave][lane] = h;
  __syncthreads();
  float o = b2[lane];
  #pragma unroll 8
  for (int j = 0; j < 64; ++j) o += sH[wave][j] * sW2[j * 64 + lane];
  o = fmaxf(o, 0.f);
  if (n < N) out[n * 64 + lane] = o;
}

// ------------- edge encoder layer1 + degree count ---------------------------
__global__ __launch_bounds__(256) void edge_l1(
    const float* __restrict__ ea, const float* __restrict__ w1,
    const float* __restrict__ b1, const int* __restrict__ ei,
    int* __restrict__ deg, float* __restrict__ h, int E)
{
  int tid = blockIdx.x * 256 + threadIdx.x;
  int e = tid >> 6, lane = tid & 63;
  if (e >= E) return;
  float v = b1[lane];
  #pragma unroll
  for (int i = 0; i < 4; ++i) v += ea[e * 4 + i] * w1[i * 64 + lane];
  h[e * 64 + lane] = fmaxf(v, 0.f);
  if (lane == 0) {
    atomicAdd(&deg[ei[E + e]], 1);
    atomicAdd(&deg[ei[e]], 1);
  }
}

// ------------- generic tiled fp32 SGEMM: C = op(A@W + bias [+ res]) ---------
// A[M,K] (lda=K), W[K,Ncols] row-major (ldw=Ncols), grid.y = Ncols/64.
__global__ __launch_bounds__(256) void sgemm64(
    const float* __restrict__ A, int lda,
    const float* __restrict__ W, int ldw,
    const float* __restrict__ bias, const float* __restrict__ res,
    float* __restrict__ C, int ldc, int M, int K, int doRelu)
{
  __shared__ float As[64][65];
  __shared__ float Bs[64][64];
  int tid = threadIdx.x;
  int tx = tid & 15, ty = tid >> 4;
  int row0 = blockIdx.x * 64;
  int col0 = blockIdx.y * 64;
  float acc[4][4] = {};
  for (int k0 = 0; k0 < K; k0 += 64) {
    #pragma unroll
    for (int it = 0; it < 4; ++it) {
      int fid = tid + it * 256;
      int r = fid >> 4, c4 = (fid & 15) * 4;
      float4 a = make_float4(0.f, 0.f, 0.f, 0.f);
      int gr = row0 + r;
      if (gr < M) a = *(const float4*)(A + (size_t)gr * lda + k0 + c4);
      As[r][c4 + 0] = a.x; As[r][c4 + 1] = a.y;
      As[r][c4 + 2] = a.z; As[r][c4 + 3] = a.w;
    }
    #pragma unroll
    for (int it = 0; it < 4; ++it) {
      int fid = tid + it * 256;
      int kk = fid >> 4, c4 = (fid & 15) * 4;
      float4 b = *(const float4*)(W + (size_t)(k0 + kk) * ldw + col0 + c4);
      *(float4*)&Bs[kk][c4] = b;
    }
    __syncthreads();
    #pragma unroll 16
    for (int k = 0; k < 64; ++k) {
      float4 b = *(const float4*)&Bs[k][tx * 4];
      float a[4];
      #pragma unroll
      for (int i = 0; i < 4; ++i) a[i] = As[ty * 4 + i][k];
      #pragma unroll
      for (int i = 0; i < 4; ++i) {
        acc[i][0] += a[i] * b.x;
        acc[i][1] += a[i] * b.y;
        acc[i][2] += a[i] * b.z;
        acc[i][3] += a[i] * b.w;
      }
    }
    __syncthreads();
  }
  #pragma unroll
  for (int i = 0; i < 4; ++i) {
    int r = row0 + ty * 4 + i;
    if (r >= M) continue;
    #pragma unroll
    for (int j = 0; j < 4; ++j) {
      int c = col0 + tx * 4 + j;
      float vv = acc[i][j] + bias[c];
      if (doRelu) vv = fmaxf(vv, 0.f);
      if (res) vv += res[(size_t)r * ldc + c];
      C[(size_t)r * ldc + c] = vv;
    }
  }
}

// ------------- scatter edge features into agg at both endpoints -------------
__global__ __launch_bounds__(256) void scatter_f(
    const float* __restrict__ f, const int* __restrict__ ei,
    float* __restrict__ agg, int E)
{
  int tid = blockIdx.x * 256 + threadIdx.x;
  int e = tid >> 6, lane = tid & 63;
  if (e >= E) return;
  float v = f[e * 64 + lane];
  atomicAdd(&agg[(size_t)ei[E + e] * 64 + lane], v);
  atomicAdd(&agg[(size_t)ei[e] * 64 + lane], v);
}

// ------------- comb = LN(cat(node, agg-node)) -------------------------------
__global__ __launch_bounds__(256) void comb_ln(
    const float* __restrict__ node, const float* __restrict__ agg,
    const float* __restrict__ g, const float* __restrict__ b,
    float* __restrict__ comb, int N)
{
  int tid = blockIdx.x * 256 + threadIdx.x;
  int n = tid >> 6, lane = tid & 63;
  if (n >= N) return;
  float v0 = node[(size_t)n * 64 + lane];
  float v1 = agg[(size_t)n * 64 + lane] - v0;
  float s = wave_reduce_sum(v0 + v1);
  float ss = wave_reduce_sum(v0 * v0 + v1 * v1);
  float mean = s * (1.f / 128.f);
  float var = ss * (1.f / 128.f) - mean * mean;
  float rstd = rsqrtf(var + 1e-5f);
  comb[(size_t)n * 128 + lane]      = (v0 - mean) * rstd * g[lane] + b[lane];
  comb[(size_t)n * 128 + 64 + lane] = (v1 - mean) * rstd * g[64 + lane] + b[64 + lane];
}

// ------------- CSR range allocation (wave scan + one atomic per wave) -------
__global__ __launch_bounds__(64) void alloc_ranges(
    const int* __restrict__ deg, int* __restrict__ base,
    int* __restrict__ fillcur, int* __restrict__ cursor, int N)
{
  int lane = threadIdx.x;
  int n = blockIdx.x * 64 + lane;
  int d = (n < N) ? deg[n] : 0;
  int s = d;
  #pragma unroll
  for (int o = 1; o < 64; o <<= 1) {
    int t = __shfl_up(s, o);
    if (lane >= o) s += t;
  }
  int tot = __shfl(s, 63);
  int wb = 0;
  if (lane == 63) wb = atomicAdd(cursor, tot);
  wb = __shfl(wb, 63);
  if (n < N) { base[n] = wb + s - d; fillcur[n] = wb + s - d; }
}

__global__ __launch_bounds__(256) void csr_fill(
    const int* __restrict__ ei, int* __restrict__ fillcur,
    int* __restrict__ csr_send, int E)
{
  int e = blockIdx.x * 256 + threadIdx.x;
  if (e >= E) return;
  int a = ei[e], b = ei[E + e];
  csr_send[atomicAdd(&fillcur[b], 1)] = a;
  csr_send[atomicAdd(&fillcur[a], 1)] = b;
}

// ------------- attention (online softmax per dst) + skip + LN ---------------
__global__ __launch_bounds__(256) void attn_ln(
    const float* __restrict__ q, const float* __restrict__ k,
    const float* __restrict__ v, const float* __restrict__ sbuf,
    const int* __restrict__ base, const int* __restrict__ deg,
    const int* __restrict__ csr_send,
    const float* __restrict__ g, const float* __restrict__ bb,
    float* __restrict__ outn, int N)
{
  int tid = blockIdx.x * 256 + threadIdx.x;
  int n = tid >> 6, lane = tid & 63;
  if (n >= N) return;
  float qh[4], m[4], l[4], acc[4];
  #pragma unroll
  for (int h = 0; h < 4; ++h) {
    qh[h] = q[(size_t)n * 256 + h * 64 + lane];
    m[h] = -1e30f; l[h] = 0.f; acc[h] = 0.f;
  }
  int b0 = base[n], dn = deg[n];
  for (int j = 0; j < dn; ++j) {
    int s = csr_send[b0 + j];
    float sc[4];
    #pragma unroll
    for (int h = 0; h < 4; ++h) {
      float p = qh[h] * k[(size_t)s * 256 + h * 64 + lane];
      sc[h] = wave_reduce_sum(p) * 0.125f;
    }
    #pragma unroll
    for (int h = 0; h < 4; ++h) {
      float vv = v[(size_t)s * 256 + h * 64 + lane];
      float mn = fmaxf(m[h], sc[h]);
      float e1 = __expf(m[h] - mn);
      float p = __expf(sc[h] - mn);
      l[h] = l[h] * e1 + p;
      acc[h] = acc[h] * e1 + p * vv;
      m[h] = mn;
    }
  }
  float y[4], s1 = 0.f, s2 = 0.f;
  #pragma unroll
  for (int h = 0; h < 4; ++h) {
    float a = acc[h] / (l[h] + 1e-16f);
    y[h] = a + sbuf[(size_t)n * 256 + h * 64 + lane];
    s1 += y[h]; s2 += y[h] * y[h];
  }
  s1 = wave_reduce_sum(s1);
  s2 = wave_reduce_sum(s2);
  float mean = s1 * (1.f / 256.f);
  float var = s2 * (1.f / 256.f) - mean * mean;
  float rstd = rsqrtf(var + 1e-5f);
  #pragma unroll
  for (int h = 0; h < 4; ++h)
    outn[(size_t)n * 256 + h * 64 + lane] =
        (y[h] - mean) * rstd * g[h * 64 + lane] + bb[h * 64 + lane];
}

// ------------- classifier input gather: clf = cat(node[start], node[end]) ---
__global__ __launch_bounds__(256) void clf_gather(
    const float* __restrict__ node, const int* __restrict__ ei,
    float* __restrict__ clf, int E)
{
  int tid = blockIdx.x * 256 + threadIdx.x;
  int e = tid >> 7, c = tid & 127;
  if (e >= E) return;
  int src = (c < 64) ? ei[e] : ei[E + e];
  clf[(size_t)e * 128 + c] = node[(size_t)src * 64 + (c & 63)];
}

// ------------- classifier layer2: out = h1 @ ec_w2 + b2 ---------------------
__global__ __launch_bounds__(256) void clf_out(
    const float* __restrict__ h1, const float* __restrict__ w2,
    const float* __restrict__ b2, float* __restrict__ out, int E)
{
  int tid = blockIdx.x * 256 + threadIdx.x;
  int e = tid >> 6, lane = tid & 63;
  if (e >= E) return;
  float p = h1[(size_t)e * 64 + lane] * w2[lane];
  p = wave_reduce_sum(p);
  if (lane == 0) out[e] = p + b2[0];
}

extern "C" void kernel_launch(void* const* d_in, const int* in_sizes, int n_in,
                              void* d_out, int out_size, void* d_ws, size_t ws_size,
                              hipStream_t stream)
{
  const float* x     = (const float*)d_in[0];
  const float* ea    = (const float*)d_in[1];
  const float* ne_w1 = (const float*)d_in[2];
  const float* ne_b1 = (const float*)d_in[3];
  const float* ne_w2 = (const float*)d_in[4];
  const float* ne_b2 = (const float*)d_in[5];
  const float* ee_w1 = (const float*)d_in[6];
  const float* ee_b1 = (const float*)d_in[7];
  const float* ee_w2 = (const float*)d_in[8];
  const float* ee_b2 = (const float*)d_in[9];
  const float* lnc_g = (const float*)d_in[10];
  const float* lnc_b = (const float*)d_in[11];
  const float* tq_w  = (const float*)d_in[12];
  const float* tq_b  = (const float*)d_in[13];
  const float* tk_w  = (const float*)d_in[14];
  const float* tk_b  = (const float*)d_in[15];
  const float* tv_w  = (const float*)d_in[16];
  const float* tv_b  = (const float*)d_in[17];
  const float* ts_w  = (const float*)d_in[18];
  const float* ts_b  = (const float*)d_in[19];
  const float* lnt_g = (const float*)d_in[20];
  const float* lnt_b = (const float*)d_in[21];
  const float* pn_w  = (const float*)d_in[22];
  const float* pn_b  = (const float*)d_in[23];
  // d_in[24], d_in[25] = pe_w, pe_b : dead code in the reference (n_iter=1)
  const float* ec_w1 = (const float*)d_in[26];
  const float* ec_b1 = (const float*)d_in[27];
  const float* ec_w2 = (const float*)d_in[28];
  const float* ec_b2 = (const float*)d_in[29];
  const int*   ei    = (const int*)d_in[30];

  const int N = in_sizes[0] / 6;
  const int E = in_sizes[1] / 4;
  float* out = (float*)d_out;

  char* w = (char*)d_ws;
  size_t off = 0;
  auto alloc = [&](size_t bytes) -> char* {
    char* p = w + off;
    off = (off + bytes + 255) & ~(size_t)255;
    return p;
  };
  float* node0  = (float*)alloc((size_t)N * 64 * 4);
  float* aggbuf = (float*)alloc((size_t)N * 64 * 4);    // agg, later node_new
  float* comb   = (float*)alloc((size_t)N * 128 * 4);
  float* qbuf   = (float*)alloc((size_t)N * 256 * 4);   // q, later outn
  float* kbuf   = (float*)alloc((size_t)N * 256 * 4);   // k; later clf (spans k+v)
  float* vbuf   = (float*)alloc((size_t)N * 256 * 4);   // f (edge feats), later v
  float* sbuf   = (float*)alloc((size_t)N * 256 * 4);   // h_edge, later s, later h1
  int* deg      = (int*)alloc((size_t)N * 4);
  int* base     = (int*)alloc((size_t)N * 4);
  int* fillcur  = (int*)alloc((size_t)N * 4);
  int* csr_send = (int*)alloc((size_t)2 * E * 4);
  int* cursor   = (int*)alloc(256);

  float* h_edge   = sbuf;          // [E,64]
  float* f_edge   = vbuf;          // [E,64]
  float* outn     = qbuf;          // in-place over q (each wave owns its row)
  float* node_new = aggbuf;        // agg dead after comb_ln
  float* clf      = kbuf;          // [E,128] spans kbuf+vbuf (dead after attn)
  float* h1       = sbuf;          // [E,64]  (s dead after attn)

  hipMemsetAsync(aggbuf, 0, (size_t)N * 64 * 4, stream);
  hipMemsetAsync(deg, 0, (size_t)N * 4, stream);
  hipMemsetAsync(cursor, 0, 4, stream);

  // 1. node encoder
  node_encoder<<<(N + 3) / 4, 256, 0, stream>>>(x, ne_w1, ne_b1, ne_w2, ne_b2, node0, N);
  // 2. edge encoder layer1 + degree counts
  edge_l1<<<(E * 64 + 255) / 256, 256, 0, stream>>>(ea, ee_w1, ee_b1, ei, deg, h_edge, E);
  // 3. edge encoder layer2 (GEMM, relu)
  sgemm64<<<dim3((E + 63) / 64, 1), 256, 0, stream>>>(h_edge, 64, ee_w2, 64, ee_b2,
                                                      nullptr, f_edge, 64, E, 64, 1);
  // 4. scatter into agg (both endpoints)
  scatter_f<<<(E * 64 + 255) / 256, 256, 0, stream>>>(f_edge, ei, aggbuf, E);
  // 5. CSR build
  alloc_ranges<<<(N + 63) / 64, 64, 0, stream>>>(deg, base, fillcur, cursor, N);
  csr_fill<<<(E + 255) / 256, 256, 0, stream>>>(ei, fillcur, csr_send, E);
  // 6. comb = LN(cat(node, agg-node))
  comb_ln<<<(N * 64 + 255) / 256, 256, 0, stream>>>(node0, aggbuf, lnc_g, lnc_b, comb, N);
  // 7. Q,K,V,S projections (four 50000x128x256 SGEMMs)
  sgemm64<<<dim3((N + 63) / 64, 4), 256, 0, stream>>>(comb, 128, tq_w, 256, tq_b,
                                                      nullptr, qbuf, 256, N, 128, 0);
  sgemm64<<<dim3((N + 63) / 64, 4), 256, 0, stream>>>(comb, 128, tk_w, 256, tk_b,
                                                      nullptr, kbuf, 256, N, 128, 0);
  sgemm64<<<dim3((N + 63) / 64, 4), 256, 0, stream>>>(comb, 128, tv_w, 256, tv_b,
                                                      nullptr, vbuf, 256, N, 128, 0);
  sgemm64<<<dim3((N + 63) / 64, 4), 256, 0, stream>>>(comb, 128, ts_w, 256, ts_b,
                                                      nullptr, sbuf, 256, N, 128, 0);
  // 8. attention + skip + LN  (writes outn over q in place)
  attn_ln<<<(N * 64 + 255) / 256, 256, 0, stream>>>(qbuf, kbuf, vbuf, sbuf, base, deg,
                                                    csr_send, lnt_g, lnt_b, outn, N);
  // 9. node projection + residual
  sgemm64<<<dim3((N + 63) / 64, 1), 256, 0, stream>>>(outn, 256, pn_w, 64, pn_b,
                                                      node0, node_new, 64, N, 256, 0);
  // 10. classifier
  clf_gather<<<((size_t)E * 128 + 255) / 256, 256, 0, stream>>>(node_new, ei, clf, E);
  sgemm64<<<dim3((E + 63) / 64, 1), 256, 0, stream>>>(clf, 128, ec_w1, 64, ec_b1,
                                                      nullptr, h1, 64, E, 128, 1);
  clf_out<<<(E * 64 + 255) / 256, 256, 0, stream>>>(h1, ec_w2, ec_b2, out, E);
}

// Round 2
// 425.103 us; speedup vs baseline: 1.9762x; 1.9762x over previous
//
#include <hip/hip_runtime.h>
#include <hip/hip_bf16.h>

// N=50000 nodes, E=200000 directed edges, H=4 heads, D=64, NODE_IN=6, EDGE_IN=4

typedef __attribute__((ext_vector_type(8))) short short8;   // 8 bf16 = 4 VGPRs
typedef __attribute__((ext_vector_type(4))) float f32x4;

__device__ __forceinline__ float wave_reduce_sum(float p) {
  #pragma unroll
  for (int o = 32; o; o >>= 1) p += __shfl_xor(p, o);
  return p;
}
__device__ __forceinline__ ushort f2b(float x) {  // fp32 -> bf16 RNE
  union { float f; unsigned u; } a; a.f = x;
  unsigned r = a.u + 0x7FFF + ((a.u >> 16) & 1);
  return (ushort)(r >> 16);
}
__device__ __forceinline__ float b2f(ushort u) {
  return __uint_as_float((unsigned)u << 16);
}

// ---------------- node encoder: node0 = relu(relu(x@W1+b1)@W2+b2) (fp32) ----
__global__ __launch_bounds__(256) void node_encoder(
    const float* __restrict__ x, const float* __restrict__ w1,
    const float* __restrict__ b1, const float* __restrict__ w2,
    const float* __restrict__ b2, float* __restrict__ out, int N)
{
  __shared__ float sW2[64 * 64];
  __shared__ float sH[4][64];
  int tid = threadIdx.x;
  for (int i = tid; i < 64 * 64; i += 256) sW2[i] = w2[i];
  int wave = tid >> 6, lane = tid & 63;
  int n = blockIdx.x * 4 + wave;
  int nc = n < N ? n : (N - 1);
  float h = b1[lane];
  #pragma unroll
  for (int i = 0; i < 6; ++i) h += x[nc * 6 + i] * w1[i * 64 + lane];
  h = fmaxf(h, 0.f);
  sH[wave][lane] = h;
  __syncthreads();
  float o = b2[lane];
  #pragma unroll 8
  for (int j = 0; j < 64; ++j) o += sH[wave][j] * sW2[j * 64 + lane];
  o = fmaxf(o, 0.f);
  if (n < N) out[n * 64 + lane] = o;
}

// ------------- edge encoder layer1 (bf16 out) + degree count ----------------
__global__ __launch_bounds__(256) void edge_l1(
    const float* __restrict__ ea, const float* __restrict__ w1,
    const float* __restrict__ b1, const int* __restrict__ ei,
    int* __restrict__ deg, ushort* __restrict__ h, int E)
{
  int tid = blockIdx.x * 256 + threadIdx.x;
  int e = tid >> 6, lane = tid & 63;
  if (e >= E) return;
  float v = b1[lane];
  #pragma unroll
  for (int i = 0; i < 4; ++i) v += ea[e * 4 + i] * w1[i * 64 + lane];
  h[(size_t)e * 64 + lane] = f2b(fmaxf(v, 0.f));
  if (lane == 0) {
    atomicAdd(&deg[ei[E + e]], 1);
    atomicAdd(&deg[ei[e]], 1);
  }
}

// ------------- weight prep: transpose + cast to bf16 ------------------------
__global__ __launch_bounds__(256) void prep_weights(
    const float* __restrict__ tq_w, const float* __restrict__ tk_w,
    const float* __restrict__ tv_w, const float* __restrict__ ts_w,
    const float* __restrict__ tq_b, const float* __restrict__ tk_b,
    const float* __restrict__ tv_b, const float* __restrict__ ts_b,
    const float* __restrict__ pn_w, const float* __restrict__ ec_w1,
    const float* __restrict__ ee_w2,
    ushort* __restrict__ wqkvsT, float* __restrict__ bqkvs,
    ushort* __restrict__ pnT, ushort* __restrict__ ec1T,
    ushort* __restrict__ ee2T)
{
  int idx = blockIdx.x * 256 + threadIdx.x;
  if (idx < 131072) {                       // wqkvsT [1024][128]
    int nn = idx >> 7, k = idx & 127;
    int g = nn >> 8, c = nn & 255;
    const float* w = (g == 0) ? tq_w : (g == 1) ? tk_w : (g == 2) ? tv_w : ts_w;
    wqkvsT[idx] = f2b(w[k * 256 + c]);
  } else if (idx < 147456) {                // pnT [64][256]
    int i = idx - 131072; int c = i >> 8, k = i & 255;
    pnT[i] = f2b(pn_w[k * 64 + c]);
  } else if (idx < 155648) {                // ec1T [64][128]
    int i = idx - 147456; int c = i >> 7, k = i & 127;
    ec1T[i] = f2b(ec_w1[k * 64 + c]);
  } else if (idx < 159744) {                // ee2T [64][64]
    int i = idx - 155648; int c = i >> 6, k = i & 63;
    ee2T[i] = f2b(ee_w2[k * 64 + c]);
  } else if (idx < 160768) {                // bqkvs [1024]
    int i = idx - 159744; int g = i >> 8, c = i & 255;
    const float* b = (g == 0) ? tq_b : (g == 1) ? tk_b : (g == 2) ? tv_b : ts_b;
    bqkvs[i] = b[c];
  }
}

// ------------- generic bf16 MFMA GEMM: C = op(A@B + bias [+res]) ------------
// A [M,lda] bf16, BT [Ntot][K] bf16 (pre-transposed), tile 64x64, 4 waves.
__global__ __launch_bounds__(256) void mgemm(
    const ushort* __restrict__ A, int lda, int M,
    const ushort* __restrict__ BT, const float* __restrict__ bias, int K,
    float* __restrict__ outF, ushort* __restrict__ outB, int ldo,
    const float* __restrict__ res, int ldres, int doRelu)
{
  __shared__ ushort As[64 * 136];
  __shared__ ushort Bs[64 * 136];
  int tid = threadIdx.x;
  int wv = tid >> 6, lane = tid & 63;
  int r16 = lane & 15, g4 = lane >> 4;
  int row0 = blockIdx.x * 64, col0 = blockIdx.y * 64;
  f32x4 acc[4] = {};
  for (int k0 = 0; k0 < K; k0 += 128) {
    int BK = K - k0; if (BK > 128) BK = 128;
    int csh = (BK == 64) ? 3 : 4;
    int cmask = (1 << csh) - 1;
    int tot = 64 << csh;
    for (int idx = tid; idx < tot; idx += 256) {
      int r = idx >> csh, c = idx & cmask;
      int gr = row0 + r; if (gr >= M) gr = M - 1;
      *(short8*)&As[r * 136 + c * 8] =
          *(const short8*)&A[(size_t)gr * lda + k0 + c * 8];
      *(short8*)&Bs[r * 136 + c * 8] =
          *(const short8*)&BT[(size_t)(col0 + r) * K + k0 + c * 8];
    }
    __syncthreads();
    int ks = BK >> 5;
    for (int kk = 0; kk < ks; ++kk) {
      short8 a = *(const short8*)&As[(wv * 16 + r16) * 136 + kk * 32 + g4 * 8];
      #pragma unroll
      for (int ct = 0; ct < 4; ++ct) {
        short8 b = *(const short8*)&Bs[(ct * 16 + r16) * 136 + kk * 32 + g4 * 8];
        acc[ct] = __builtin_amdgcn_mfma_f32_16x16x32_bf16(a, b, acc[ct], 0, 0, 0);
      }
    }
    __syncthreads();
  }
  #pragma unroll
  for (int ct = 0; ct < 4; ++ct) {
    int c = col0 + ct * 16 + r16;
    float bs = bias[c];
    #pragma unroll
    for (int j = 0; j < 4; ++j) {
      int r = row0 + wv * 16 + g4 * 4 + j;
      if (r >= M) continue;
      float vv = acc[ct][j] + bs;
      if (doRelu) vv = fmaxf(vv, 0.f);
      if (res) vv += res[(size_t)r * ldres + c];
      if (outF) outF[(size_t)r * ldo + c] = vv;
      if (outB) outB[(size_t)r * ldo + c] = f2b(vv);
    }
  }
}

// ------------- scatter edge features into agg at both endpoints -------------
__global__ __launch_bounds__(256) void scatter_f(
    const float* __restrict__ f, const int* __restrict__ ei,
    float* __restrict__ agg, int E)
{
  int tid = blockIdx.x * 256 + threadIdx.x;
  int e = tid >> 6, lane = tid & 63;
  if (e >= E) return;
  float v = f[(size_t)e * 64 + lane];
  atomicAdd(&agg[(size_t)ei[E + e] * 64 + lane], v);
  atomicAdd(&agg[(size_t)ei[e] * 64 + lane], v);
}

// ------------- comb = LN(cat(node, agg-node))  (bf16 out) -------------------
__global__ __launch_bounds__(256) void comb_ln(
    const float* __restrict__ node, const float* __restrict__ agg,
    const float* __restrict__ g, const float* __restrict__ b,
    ushort* __restrict__ comb, int N)
{
  int tid = blockIdx.x * 256 + threadIdx.x;
  int n = tid >> 6, lane = tid & 63;
  if (n >= N) return;
  float v0 = node[(size_t)n * 64 + lane];
  float v1 = agg[(size_t)n * 64 + lane] - v0;
  float s = wave_reduce_sum(v0 + v1);
  float ss = wave_reduce_sum(v0 * v0 + v1 * v1);
  float mean = s * (1.f / 128.f);
  float var = ss * (1.f / 128.f) - mean * mean;
  float rstd = rsqrtf(var + 1e-5f);
  comb[(size_t)n * 128 + lane]      = f2b((v0 - mean) * rstd * g[lane] + b[lane]);
  comb[(size_t)n * 128 + 64 + lane] = f2b((v1 - mean) * rstd * g[64 + lane] + b[64 + lane]);
}

// ------------- CSR range allocation -----------------------------------------
__global__ __launch_bounds__(64) void alloc_ranges(
    const int* __restrict__ deg, int* __restrict__ base,
    int* __restrict__ fillcur, int* __restrict__ cursor, int N)
{
  int lane = threadIdx.x;
  int n = blockIdx.x * 64 + lane;
  int d = (n < N) ? deg[n] : 0;
  int s = d;
  #pragma unroll
  for (int o = 1; o < 64; o <<= 1) {
    int t = __shfl_up(s, o);
    if (lane >= o) s += t;
  }
  int tot = __shfl(s, 63);
  int wb = 0;
  if (lane == 63) wb = atomicAdd(cursor, tot);
  wb = __shfl(wb, 63);
  if (n < N) { base[n] = wb + s - d; fillcur[n] = wb + s - d; }
}

__global__ __launch_bounds__(256) void csr_fill(
    const int* __restrict__ ei, int* __restrict__ fillcur,
    int* __restrict__ csr_send, int E)
{
  int e = blockIdx.x * 256 + threadIdx.x;
  if (e >= E) return;
  int a = ei[e], b = ei[E + e];
  csr_send[atomicAdd(&fillcur[b], 1)] = a;
  csr_send[atomicAdd(&fillcur[a], 1)] = b;
}

// ------------- attention + skip + LN, all bf16, head per 16-lane group ------
// qkvs[n][0:256]=q, [256:512]=k, [512:768]=v, [768:1024]=s; outn written over q.
__global__ __launch_bounds__(256) void attn_ln2(
    ushort* __restrict__ qkvs, const int* __restrict__ base,
    const int* __restrict__ deg, const int* __restrict__ csr_send,
    const float* __restrict__ g, const float* __restrict__ bb, int N)
{
  int tid = blockIdx.x * 256 + threadIdx.x;
  int n = tid >> 6, lane = tid & 63;
  if (n >= N) return;
  int dbase = (lane >> 4) * 64 + (lane & 15) * 4;   // head*64 + 4-dim slot
  ushort4 qu = *(const ushort4*)(qkvs + (size_t)n * 1024 + dbase);
  float q0 = b2f(qu.x), q1 = b2f(qu.y), q2 = b2f(qu.z), q3 = b2f(qu.w);
  float m = -1e30f, l = 0.f, a0 = 0.f, a1 = 0.f, a2 = 0.f, a3 = 0.f;
  int b0 = base[n], dn = deg[n];
  for (int j = 0; j < dn; ++j) {
    int s = csr_send[b0 + j];
    const ushort* kp = qkvs + (size_t)s * 1024 + 256 + dbase;
    ushort4 ku = *(const ushort4*)kp;
    ushort4 vu = *(const ushort4*)(kp + 256);
    float p = q0 * b2f(ku.x) + q1 * b2f(ku.y) + q2 * b2f(ku.z) + q3 * b2f(ku.w);
    p += __shfl_xor(p, 1); p += __shfl_xor(p, 2);
    p += __shfl_xor(p, 4); p += __shfl_xor(p, 8);
    p *= 0.125f;
    float mn = fmaxf(m, p);
    float e1 = __expf(m - mn), pe = __expf(p - mn);
    l = l * e1 + pe;
    a0 = a0 * e1 + pe * b2f(vu.x);
    a1 = a1 * e1 + pe * b2f(vu.y);
    a2 = a2 * e1 + pe * b2f(vu.z);
    a3 = a3 * e1 + pe * b2f(vu.w);
    m = mn;
  }
  ushort4 su = *(const ushort4*)(qkvs + (size_t)n * 1024 + 768 + dbase);
  float rl = 1.f / (l + 1e-16f);
  float y0 = a0 * rl + b2f(su.x), y1 = a1 * rl + b2f(su.y);
  float y2 = a2 * rl + b2f(su.z), y3 = a3 * rl + b2f(su.w);
  float s1 = wave_reduce_sum(y0 + y1 + y2 + y3);
  float s2 = wave_reduce_sum(y0 * y0 + y1 * y1 + y2 * y2 + y3 * y3);
  float mean = s1 * (1.f / 256.f);
  float var = s2 * (1.f / 256.f) - mean * mean;
  float rstd = rsqrtf(var + 1e-5f);
  ushort4 o;
  o.x = f2b((y0 - mean) * rstd * g[dbase + 0] + bb[dbase + 0]);
  o.y = f2b((y1 - mean) * rstd * g[dbase + 1] + bb[dbase + 1]);
  o.z = f2b((y2 - mean) * rstd * g[dbase + 2] + bb[dbase + 2]);
  o.w = f2b((y3 - mean) * rstd * g[dbase + 3] + bb[dbase + 3]);
  *(ushort4*)(qkvs + (size_t)n * 1024 + dbase) = o;
}

// ------------- classifier, fully fused: gather + GEMM + relu + dot(w2) ------
__global__ __launch_bounds__(256) void clf_fused(
    const ushort* __restrict__ nodeB, const int* __restrict__ ei,
    const ushort* __restrict__ ec1T, const float* __restrict__ b1,
    const float* __restrict__ w2, const float* __restrict__ b2v,
    float* __restrict__ out, int E)
{
  __shared__ ushort As[64 * 136];
  __shared__ ushort Bs[64 * 136];
  int tid = threadIdx.x;
  int wv = tid >> 6, lane = tid & 63;
  int r16 = lane & 15, g4 = lane >> 4;
  int e0 = blockIdx.x * 64;
  for (int idx = tid; idx < 1024; idx += 256) {
    int r = idx >> 4, c = idx & 15;
    int e = e0 + r; if (e >= E) e = E - 1;
    int node = (c < 8) ? ei[e] : ei[E + e];
    *(short8*)&As[r * 136 + c * 8] =
        *(const short8*)&nodeB[(size_t)node * 64 + (c & 7) * 8];
    *(short8*)&Bs[r * 136 + c * 8] = *(const short8*)&ec1T[r * 128 + c * 8];
  }
  __syncthreads();
  f32x4 acc[4] = {};
  #pragma unroll
  for (int kk = 0; kk < 4; ++kk) {
    short8 a = *(const short8*)&As[(wv * 16 + r16) * 136 + kk * 32 + g4 * 8];
    #pragma unroll
    for (int ct = 0; ct < 4; ++ct) {
      short8 b = *(const short8*)&Bs[(ct * 16 + r16) * 136 + kk * 32 + g4 * 8];
      acc[ct] = __builtin_amdgcn_mfma_f32_16x16x32_bf16(a, b, acc[ct], 0, 0, 0);
    }
  }
  float p0 = 0.f, p1 = 0.f, p2 = 0.f, p3 = 0.f;
  #pragma unroll
  for (int ct = 0; ct < 4; ++ct) {
    int c = ct * 16 + r16;
    float bb1 = b1[c], ww = w2[c];
    p0 += fmaxf(acc[ct][0] + bb1, 0.f) * ww;
    p1 += fmaxf(acc[ct][1] + bb1, 0.f) * ww;
    p2 += fmaxf(acc[ct][2] + bb1, 0.f) * ww;
    p3 += fmaxf(acc[ct][3] + bb1, 0.f) * ww;
  }
  float part[4] = {p0, p1, p2, p3};
  #pragma unroll
  for (int j = 0; j < 4; ++j) {
    float p = part[j];
    p += __shfl_xor(p, 1); p += __shfl_xor(p, 2);
    p += __shfl_xor(p, 4); p += __shfl_xor(p, 8);
    int r = e0 + wv * 16 + g4 * 4 + j;
    if (r16 == 0 && r < E) out[r] = p + b2v[0];
  }
}

extern "C" void kernel_launch(void* const* d_in, const int* in_sizes, int n_in,
                              void* d_out, int out_size, void* d_ws, size_t ws_size,
                              hipStream_t stream)
{
  const float* x     = (const float*)d_in[0];
  const float* ea    = (const float*)d_in[1];
  const float* ne_w1 = (const float*)d_in[2];
  const float* ne_b1 = (const float*)d_in[3];
  const float* ne_w2 = (const float*)d_in[4];
  const float* ne_b2 = (const float*)d_in[5];
  const float* ee_w1 = (const float*)d_in[6];
  const float* ee_b1 = (const float*)d_in[7];
  const float* ee_w2 = (const float*)d_in[8];
  const float* ee_b2 = (const float*)d_in[9];
  const float* lnc_g = (const float*)d_in[10];
  const float* lnc_b = (const float*)d_in[11];
  const float* tq_w  = (const float*)d_in[12];
  const float* tq_b  = (const float*)d_in[13];
  const float* tk_w  = (const float*)d_in[14];
  const float* tk_b  = (const float*)d_in[15];
  const float* tv_w  = (const float*)d_in[16];
  const float* tv_b  = (const float*)d_in[17];
  const float* ts_w  = (const float*)d_in[18];
  const float* ts_b  = (const float*)d_in[19];
  const float* lnt_g = (const float*)d_in[20];
  const float* lnt_b = (const float*)d_in[21];
  const float* pn_w  = (const float*)d_in[22];
  const float* pn_b  = (const float*)d_in[23];
  // d_in[24], d_in[25] = pe_w, pe_b : dead code (n_iterations=1)
  const float* ec_w1 = (const float*)d_in[26];
  const float* ec_b1 = (const float*)d_in[27];
  const float* ec_w2 = (const float*)d_in[28];
  const float* ec_b2 = (const float*)d_in[29];
  const int*   ei    = (const int*)d_in[30];

  const int N = in_sizes[0] / 6;
  const int E = in_sizes[1] / 4;
  float* out = (float*)d_out;

  char* w = (char*)d_ws;
  size_t off = 0;
  auto alloc = [&](size_t bytes) -> char* {
    char* p = w + off;
    off = (off + bytes + 255) & ~(size_t)255;
    return p;
  };
  float*  node0   = (float*)alloc((size_t)N * 64 * 4);
  float*  aggbuf  = (float*)alloc((size_t)N * 64 * 4);     // agg, later node_new
  ushort* comb    = (ushort*)alloc((size_t)N * 128 * 2);
  ushort* qkvs    = (ushort*)alloc((size_t)N * 1024 * 2);  // q|k|v|s, outn over q
  ushort* h_edge  = (ushort*)alloc((size_t)E * 64 * 2);
  float*  f_edge  = (float*)alloc((size_t)E * 64 * 4);
  ushort* nodeB   = (ushort*)alloc((size_t)N * 64 * 2);
  ushort* wqkvsT  = (ushort*)alloc(1024 * 128 * 2);
  float*  bqkvs   = (float*)alloc(1024 * 4);
  ushort* pnT     = (ushort*)alloc(64 * 256 * 2);
  ushort* ec1T    = (ushort*)alloc(64 * 128 * 2);
  ushort* ee2T    = (ushort*)alloc(64 * 64 * 2);
  int* deg      = (int*)alloc((size_t)N * 4);
  int* base     = (int*)alloc((size_t)N * 4);
  int* fillcur  = (int*)alloc((size_t)N * 4);
  int* csr_send = (int*)alloc((size_t)2 * E * 4);
  int* cursor   = (int*)alloc(256);

  float* node_new = aggbuf;  // agg dead after comb_ln

  hipMemsetAsync(aggbuf, 0, (size_t)N * 64 * 4, stream);
  hipMemsetAsync(deg, 0, (size_t)N * 4, stream);
  hipMemsetAsync(cursor, 0, 4, stream);

  // weight prep (transpose + bf16)
  prep_weights<<<(160768 + 255) / 256, 256, 0, stream>>>(
      tq_w, tk_w, tv_w, ts_w, tq_b, tk_b, tv_b, ts_b, pn_w, ec_w1, ee_w2,
      wqkvsT, bqkvs, pnT, ec1T, ee2T);
  // node encoder (fp32)
  node_encoder<<<(N + 3) / 4, 256, 0, stream>>>(x, ne_w1, ne_b1, ne_w2, ne_b2, node0, N);
  // edge encoder layer1 + degree counts
  edge_l1<<<(E * 64 + 255) / 256, 256, 0, stream>>>(ea, ee_w1, ee_b1, ei, deg, h_edge, E);
  // edge encoder layer2 (bf16 MFMA, relu, fp32 out for atomics)
  mgemm<<<dim3((E + 63) / 64, 1), 256, 0, stream>>>(
      h_edge, 64, E, ee2T, ee_b2, 64, f_edge, nullptr, 64, nullptr, 0, 1);
  // scatter into agg
  scatter_f<<<(E * 64 + 255) / 256, 256, 0, stream>>>(f_edge, ei, aggbuf, E);
  // CSR build
  alloc_ranges<<<(N + 63) / 64, 64, 0, stream>>>(deg, base, fillcur, cursor, N);
  csr_fill<<<(E + 255) / 256, 256, 0, stream>>>(ei, fillcur, csr_send, E);
  // comb = LN(cat(node, agg-node)) -> bf16
  comb_ln<<<(N * 64 + 255) / 256, 256, 0, stream>>>(node0, aggbuf, lnc_g, lnc_b, comb, N);
  // fused QKVS projection: [N,128] @ [128,1024] -> bf16 qkvs
  mgemm<<<dim3((N + 63) / 64, 16), 256, 0, stream>>>(
      comb, 128, N, wqkvsT, bqkvs, 128, nullptr, qkvs, 1024, nullptr, 0, 0);
  // attention + skip + LN (outn over q-region of qkvs)
  attn_ln2<<<(N * 64 + 255) / 256, 256, 0, stream>>>(
      qkvs, base, deg, csr_send, lnt_g, lnt_b, N);
  // node projection + residual: outn[N,256(ld1024)] @ [256,64] + node0
  mgemm<<<dim3((N + 63) / 64, 1), 256, 0, stream>>>(
      qkvs, 1024, N, pnT, pn_b, 256, node_new, nodeB, 64, node0, 64, 0);
  // classifier: gather + GEMM + relu + dot(w2) fused
  clf_fused<<<(E + 63) / 64, 256, 0, stream>>>(
      nodeB, ei, ec1T, ec_b1, ec_w2, ec_b2, out, E);
}

// Round 3
// 387.246 us; speedup vs baseline: 2.1694x; 1.0978x over previous
//
#include <hip/hip_runtime.h>
#include <hip/hip_bf16.h>

// N=50000 nodes, E=200000 directed edges, H=4 heads, D=64, NODE_IN=6, EDGE_IN=4

typedef __attribute__((ext_vector_type(8))) short short8;          // 8 bf16
typedef __attribute__((ext_vector_type(8))) unsigned short u16x8;  // 8 bf16
typedef __attribute__((ext_vector_type(4))) float f32x4;

__device__ __forceinline__ float wave_reduce_sum(float p) {
  #pragma unroll
  for (int o = 32; o; o >>= 1) p += __shfl_xor(p, o);
  return p;
}
__device__ __forceinline__ ushort f2b(float x) {  // fp32 -> bf16 RNE
  union { float f; unsigned u; } a; a.f = x;
  unsigned r = a.u + 0x7FFF + ((a.u >> 16) & 1);
  return (ushort)(r >> 16);
}
__device__ __forceinline__ float b2f(ushort u) {
  return __uint_as_float((unsigned)u << 16);
}

// ---------------- node encoder: node0 = relu(relu(x@W1+b1)@W2+b2) (fp32) ----
__global__ __launch_bounds__(256) void node_encoder(
    const float* __restrict__ x, const float* __restrict__ w1,
    const float* __restrict__ b1, const float* __restrict__ w2,
    const float* __restrict__ b2, float* __restrict__ out, int N)
{
  __shared__ float sW2[64 * 64];
  __shared__ float sH[4][64];
  int tid = threadIdx.x;
  for (int i = tid; i < 64 * 64; i += 256) sW2[i] = w2[i];
  int wave = tid >> 6, lane = tid & 63;
  int n = blockIdx.x * 4 + wave;
  int nc = n < N ? n : (N - 1);
  float h = b1[lane];
  #pragma unroll
  for (int i = 0; i < 6; ++i) h += x[nc * 6 + i] * w1[i * 64 + lane];
  h = fmaxf(h, 0.f);
  sH[wave][lane] = h;
  __syncthreads();
  float o = b2[lane];
  #pragma unroll 8
  for (int j = 0; j < 64; ++j) o += sH[wave][j] * sW2[j * 64 + lane];
  o = fmaxf(o, 0.f);
  if (n < N) out[n * 64 + lane] = o;
}

// ------------- weight prep: transpose + cast to bf16 ------------------------
__global__ __launch_bounds__(256) void prep_weights(
    const float* __restrict__ tq_w, const float* __restrict__ tk_w,
    const float* __restrict__ tv_w, const float* __restrict__ ts_w,
    const float* __restrict__ tq_b, const float* __restrict__ tk_b,
    const float* __restrict__ tv_b, const float* __restrict__ ts_b,
    const float* __restrict__ pn_w, const float* __restrict__ ec_w1,
    const float* __restrict__ ee_w2,
    ushort* __restrict__ wqkvsT, float* __restrict__ bqkvs,
    ushort* __restrict__ pnT, ushort* __restrict__ ec1T,
    ushort* __restrict__ ee2T)
{
  int idx = blockIdx.x * 256 + threadIdx.x;
  if (idx < 131072) {                       // wqkvsT [1024][128]
    int nn = idx >> 7, k = idx & 127;
    int g = nn >> 8, c = nn & 255;
    const float* w = (g == 0) ? tq_w : (g == 1) ? tk_w : (g == 2) ? tv_w : ts_w;
    wqkvsT[idx] = f2b(w[k * 256 + c]);
  } else if (idx < 147456) {                // pnT [64][256]
    int i = idx - 131072; int c = i >> 8, k = i & 255;
    pnT[i] = f2b(pn_w[k * 64 + c]);
  } else if (idx < 155648) {                // ec1T [64][128]
    int i = idx - 147456; int c = i >> 7, k = i & 127;
    ec1T[i] = f2b(ec_w1[k * 64 + c]);
  } else if (idx < 159744) {                // ee2T [64][64]
    int i = idx - 155648; int c = i >> 6, k = i & 63;
    ee2T[i] = f2b(ee_w2[k * 64 + c]);
  } else if (idx < 160768) {                // bqkvs [1024]
    int i = idx - 159744; int g = i >> 8, c = i & 255;
    const float* b = (g == 0) ? tq_b : (g == 1) ? tk_b : (g == 2) ? tv_b : ts_b;
    bqkvs[i] = b[c];
  }
}

// ------------- edge path fully fused: MLP l1 + MFMA l2 + scatter + deg ------
// One block = 64 edges. h computed in-kernel into LDS, 64x64 MFMA with ee2T,
// result tile staged to LDS, coalesced atomicAdd to agg at both endpoints.
__global__ __launch_bounds__(256) void edge_fused(
    const float* __restrict__ ea, const float* __restrict__ w1,
    const float* __restrict__ b1, const ushort* __restrict__ ee2T,
    const float* __restrict__ b2, const int* __restrict__ ei,
    int* __restrict__ deg, float* __restrict__ agg, int E)
{
  __shared__ ushort As[64 * 72];
  __shared__ ushort Bs[64 * 72];
  __shared__ float fT[64 * 65];
  __shared__ int sIA[64], sIB[64];
  int tid = threadIdx.x;
  int wv = tid >> 6, lane = tid & 63, r16 = lane & 15, g4 = lane >> 4;
  int e0 = blockIdx.x * 64;
  if (tid < 64) {
    int e = e0 + tid; int ec = e < E ? e : E - 1;
    int ia = ei[ec], ib = ei[E + ec];
    sIA[tid] = ia; sIB[tid] = ib;
    if (e < E) { atomicAdd(&deg[ia], 1); atomicAdd(&deg[ib], 1); }
  }
  // stage ee2T [64][64] -> Bs
  #pragma unroll
  for (int it = 0; it < 2; ++it) {
    int idx = tid + it * 256;
    int r = idx >> 3, c = idx & 7;
    *(short8*)&Bs[r * 72 + c * 8] = *(const short8*)&ee2T[r * 64 + c * 8];
  }
  // h = relu(ea@W1+b1), bf16, into As (thread owns col c for 16 rows)
  {
    int c = tid & 63;
    float w0 = w1[c], w1v = w1[64 + c], w2v = w1[128 + c], w3v = w1[192 + c];
    float bb = b1[c];
    int rbase = tid >> 6;
    #pragma unroll
    for (int i = 0; i < 16; ++i) {
      int r = rbase + i * 4;
      int e = e0 + r; if (e >= E) e = E - 1;
      float4 a = *(const float4*)(ea + (size_t)e * 4);
      float hv = bb + a.x * w0 + a.y * w1v + a.z * w2v + a.w * w3v;
      As[r * 72 + c] = f2b(fmaxf(hv, 0.f));
    }
  }
  __syncthreads();
  f32x4 acc[4] = {};
  #pragma unroll
  for (int kk = 0; kk < 2; ++kk) {
    short8 a = *(const short8*)&As[(wv * 16 + r16) * 72 + kk * 32 + g4 * 8];
    #pragma unroll
    for (int sc = 0; sc < 4; ++sc) {
      short8 b = *(const short8*)&Bs[(sc * 16 + r16) * 72 + kk * 32 + g4 * 8];
      acc[sc] = __builtin_amdgcn_mfma_f32_16x16x32_bf16(a, b, acc[sc], 0, 0, 0);
    }
  }
  #pragma unroll
  for (int sc = 0; sc < 4; ++sc) {
    int c = sc * 16 + r16;
    float bs = b2[c];
    #pragma unroll
    for (int j = 0; j < 4; ++j) {
      int r = wv * 16 + g4 * 4 + j;
      fT[r * 65 + c] = fmaxf(acc[sc][j] + bs, 0.f);
    }
  }
  __syncthreads();
  for (int rr = 0; rr < 16; ++rr) {
    int r = wv * 16 + rr;
    int e = e0 + r;
    if (e < E) {
      float v = fT[r * 65 + lane];
      atomicAdd(&agg[(size_t)sIA[r] * 64 + lane], v);
      atomicAdd(&agg[(size_t)sIB[r] * 64 + lane], v);
    }
  }
}

// ------------- fused QKVS GEMM: A staged once, loop 16 col tiles ------------
// Output columns permuted so k/v for one lane-slot are contiguous 16B:
// [0,256)=q | [256,768)=kv interleaved (per head h, group g: 8 = 4k + 4v) | [768,1024)=s
__global__ __launch_bounds__(256) void qkvs_gemm(
    const ushort* __restrict__ comb, const ushort* __restrict__ wqkvsT,
    const float* __restrict__ bias, ushort* __restrict__ qkvs, int N)
{
  __shared__ ushort As[64 * 136];
  __shared__ ushort Bs[2][64 * 136];
  int tid = threadIdx.x;
  int wv = tid >> 6, lane = tid & 63, r16 = lane & 15, g4 = lane >> 4;
  int row0 = blockIdx.x * 64;
  #pragma unroll
  for (int it = 0; it < 4; ++it) {
    int idx = tid + it * 256;
    int r = idx >> 4, c = idx & 15;
    int gr = row0 + r; if (gr >= N) gr = N - 1;
    *(short8*)&As[r * 136 + c * 8] = *(const short8*)&comb[(size_t)gr * 128 + c * 8];
    *(short8*)&Bs[0][r * 136 + c * 8] = *(const short8*)&wqkvsT[(size_t)r * 128 + c * 8];
  }
  for (int ct = 0; ct < 16; ++ct) {
    __syncthreads();
    if (ct < 15) {
      #pragma unroll
      for (int it = 0; it < 4; ++it) {
        int idx = tid + it * 256;
        int r = idx >> 4, c = idx & 15;
        *(short8*)&Bs[(ct + 1) & 1][r * 136 + c * 8] =
            *(const short8*)&wqkvsT[(size_t)((ct + 1) * 64 + r) * 128 + c * 8];
      }
    }
    f32x4 acc[4] = {};
    #pragma unroll
    for (int kk = 0; kk < 4; ++kk) {
      short8 a = *(const short8*)&As[(wv * 16 + r16) * 136 + kk * 32 + g4 * 8];
      #pragma unroll
      for (int sc = 0; sc < 4; ++sc) {
        short8 b = *(const short8*)&Bs[ct & 1][(sc * 16 + r16) * 136 + kk * 32 + g4 * 8];
        acc[sc] = __builtin_amdgcn_mfma_f32_16x16x32_bf16(a, b, acc[sc], 0, 0, 0);
      }
    }
    #pragma unroll
    for (int sc = 0; sc < 4; ++sc) {
      int c = ct * 64 + sc * 16 + r16;
      int p;
      if (c < 256) p = c;
      else if (c < 512) { int d = c - 256; p = 256 + (d >> 6) * 128 + ((d & 63) >> 2) * 8 + (d & 3); }
      else if (c < 768) { int d = c - 512; p = 256 + (d >> 6) * 128 + ((d & 63) >> 2) * 8 + 4 + (d & 3); }
      else p = c;
      float bs = bias[c];
      #pragma unroll
      for (int j = 0; j < 4; ++j) {
        int r = row0 + wv * 16 + g4 * 4 + j;
        if (r < N) qkvs[(size_t)r * 1024 + p] = f2b(acc[sc][j] + bs);
      }
    }
  }
}

// ------------- generic bf16 MFMA GEMM (used for proj only) ------------------
__global__ __launch_bounds__(256) void mgemm(
    const ushort* __restrict__ A, int lda, int M,
    const ushort* __restrict__ BT, const float* __restrict__ bias, int K,
    float* __restrict__ outF, ushort* __restrict__ outB, int ldo,
    const float* __restrict__ res, int ldres, int doRelu)
{
  __shared__ ushort As[64 * 136];
  __shared__ ushort Bs[64 * 136];
  int tid = threadIdx.x;
  int wv = tid >> 6, lane = tid & 63;
  int r16 = lane & 15, g4 = lane >> 4;
  int row0 = blockIdx.x * 64, col0 = blockIdx.y * 64;
  f32x4 acc[4] = {};
  for (int k0 = 0; k0 < K; k0 += 128) {
    int BK = K - k0; if (BK > 128) BK = 128;
    int csh = (BK == 64) ? 3 : 4;
    int cmask = (1 << csh) - 1;
    int tot = 64 << csh;
    for (int idx = tid; idx < tot; idx += 256) {
      int r = idx >> csh, c = idx & cmask;
      int gr = row0 + r; if (gr >= M) gr = M - 1;
      *(short8*)&As[r * 136 + c * 8] =
          *(const short8*)&A[(size_t)gr * lda + k0 + c * 8];
      *(short8*)&Bs[r * 136 + c * 8] =
          *(const short8*)&BT[(size_t)(col0 + r) * K + k0 + c * 8];
    }
    __syncthreads();
    int ks = BK >> 5;
    for (int kk = 0; kk < ks; ++kk) {
      short8 a = *(const short8*)&As[(wv * 16 + r16) * 136 + kk * 32 + g4 * 8];
      #pragma unroll
      for (int ct = 0; ct < 4; ++ct) {
        short8 b = *(const short8*)&Bs[(ct * 16 + r16) * 136 + kk * 32 + g4 * 8];
        acc[ct] = __builtin_amdgcn_mfma_f32_16x16x32_bf16(a, b, acc[ct], 0, 0, 0);
      }
    }
    __syncthreads();
  }
  #pragma unroll
  for (int ct = 0; ct < 4; ++ct) {
    int c = col0 + ct * 16 + r16;
    float bs = bias[c];
    #pragma unroll
    for (int j = 0; j < 4; ++j) {
      int r = row0 + wv * 16 + g4 * 4 + j;
      if (r >= M) continue;
      float vv = acc[ct][j] + bs;
      if (doRelu) vv = fmaxf(vv, 0.f);
      if (res) vv += res[(size_t)r * ldres + c];
      if (outF) outF[(size_t)r * ldo + c] = vv;
      if (outB) outB[(size_t)r * ldo + c] = f2b(vv);
    }
  }
}

// ------------- comb = LN(cat(node, agg-node))  (bf16 out) -------------------
__global__ __launch_bounds__(256) void comb_ln(
    const float* __restrict__ node, const float* __restrict__ agg,
    const float* __restrict__ g, const float* __restrict__ b,
    ushort* __restrict__ comb, int N)
{
  int tid = blockIdx.x * 256 + threadIdx.x;
  int n = tid >> 6, lane = tid & 63;
  if (n >= N) return;
  float v0 = node[(size_t)n * 64 + lane];
  float v1 = agg[(size_t)n * 64 + lane] - v0;
  float s = wave_reduce_sum(v0 + v1);
  float ss = wave_reduce_sum(v0 * v0 + v1 * v1);
  float mean = s * (1.f / 128.f);
  float var = ss * (1.f / 128.f) - mean * mean;
  float rstd = rsqrtf(var + 1e-5f);
  comb[(size_t)n * 128 + lane]      = f2b((v0 - mean) * rstd * g[lane] + b[lane]);
  comb[(size_t)n * 128 + 64 + lane] = f2b((v1 - mean) * rstd * g[64 + lane] + b[64 + lane]);
}

// ------------- CSR range allocation -----------------------------------------
__global__ __launch_bounds__(64) void alloc_ranges(
    const int* __restrict__ deg, int* __restrict__ base,
    int* __restrict__ fillcur, int* __restrict__ cursor, int N)
{
  int lane = threadIdx.x;
  int n = blockIdx.x * 64 + lane;
  int d = (n < N) ? deg[n] : 0;
  int s = d;
  #pragma unroll
  for (int o = 1; o < 64; o <<= 1) {
    int t = __shfl_up(s, o);
    if (lane >= o) s += t;
  }
  int tot = __shfl(s, 63);
  int wb = 0;
  if (lane == 63) wb = atomicAdd(cursor, tot);
  wb = __shfl(wb, 63);
  if (n < N) { base[n] = wb + s - d; fillcur[n] = wb + s - d; }
}

__global__ __launch_bounds__(256) void csr_fill(
    const int* __restrict__ ei, int* __restrict__ fillcur,
    int* __restrict__ csr_send, int E)
{
  int e = blockIdx.x * 256 + threadIdx.x;
  if (e >= E) return;
  int a = ei[e], b = ei[E + e];
  csr_send[atomicAdd(&fillcur[b], 1)] = a;
  csr_send[atomicAdd(&fillcur[a], 1)] = b;
}

// ------------- attention + skip + LN; kv read as one 16B load ---------------
__global__ __launch_bounds__(256) void attn_ln2(
    ushort* __restrict__ qkvs, const int* __restrict__ base,
    const int* __restrict__ deg, const int* __restrict__ csr_send,
    const float* __restrict__ g, const float* __restrict__ bb, int N)
{
  int tid = blockIdx.x * 256 + threadIdx.x;
  int n = tid >> 6, lane = tid & 63;
  if (n >= N) return;
  int dbase = (lane >> 4) * 64 + (lane & 15) * 4;              // head*64 + slot
  int kvoff = 256 + (lane >> 4) * 128 + (lane & 15) * 8;       // interleaved kv
  ushort4 qu = *(const ushort4*)(qkvs + (size_t)n * 1024 + dbase);
  float q0 = b2f(qu.x), q1 = b2f(qu.y), q2 = b2f(qu.z), q3 = b2f(qu.w);
  float m = -1e30f, l = 0.f, a0 = 0.f, a1 = 0.f, a2 = 0.f, a3 = 0.f;
  int b0 = base[n], dn = deg[n];
  for (int j = 0; j < dn; ++j) {
    int s = csr_send[b0 + j];
    u16x8 kv = *(const u16x8*)(qkvs + (size_t)s * 1024 + kvoff);
    float p = q0 * b2f((ushort)kv[0]) + q1 * b2f((ushort)kv[1]) +
              q2 * b2f((ushort)kv[2]) + q3 * b2f((ushort)kv[3]);
    p += __shfl_xor(p, 1); p += __shfl_xor(p, 2);
    p += __shfl_xor(p, 4); p += __shfl_xor(p, 8);
    p *= 0.125f;
    float mn = fmaxf(m, p);
    float e1 = __expf(m - mn), pe = __expf(p - mn);
    l = l * e1 + pe;
    a0 = a0 * e1 + pe * b2f((ushort)kv[4]);
    a1 = a1 * e1 + pe * b2f((ushort)kv[5]);
    a2 = a2 * e1 + pe * b2f((ushort)kv[6]);
    a3 = a3 * e1 + pe * b2f((ushort)kv[7]);
    m = mn;
  }
  ushort4 su = *(const ushort4*)(qkvs + (size_t)n * 1024 + 768 + dbase);
  float rl = 1.f / (l + 1e-16f);
  float y0 = a0 * rl + b2f(su.x), y1 = a1 * rl + b2f(su.y);
  float y2 = a2 * rl + b2f(su.z), y3 = a3 * rl + b2f(su.w);
  float s1 = wave_reduce_sum(y0 + y1 + y2 + y3);
  float s2 = wave_reduce_sum(y0 * y0 + y1 * y1 + y2 * y2 + y3 * y3);
  float mean = s1 * (1.f / 256.f);
  float var = s2 * (1.f / 256.f) - mean * mean;
  float rstd = rsqrtf(var + 1e-5f);
  ushort4 o;
  o.x = f2b((y0 - mean) * rstd * g[dbase + 0] + bb[dbase + 0]);
  o.y = f2b((y1 - mean) * rstd * g[dbase + 1] + bb[dbase + 1]);
  o.z = f2b((y2 - mean) * rstd * g[dbase + 2] + bb[dbase + 2]);
  o.w = f2b((y3 - mean) * rstd * g[dbase + 3] + bb[dbase + 3]);
  *(ushort4*)(qkvs + (size_t)n * 1024 + dbase) = o;
}

// ------------- classifier, fully fused: gather + GEMM + relu + dot(w2) ------
__global__ __launch_bounds__(256) void clf_fused(
    const ushort* __restrict__ nodeB, const int* __restrict__ ei,
    const ushort* __restrict__ ec1T, const float* __restrict__ b1,
    const float* __restrict__ w2, const float* __restrict__ b2v,
    float* __restrict__ out, int E)
{
  __shared__ ushort As[64 * 136];
  __shared__ ushort Bs[64 * 136];
  int tid = threadIdx.x;
  int wv = tid >> 6, lane = tid & 63;
  int r16 = lane & 15, g4 = lane >> 4;
  int e0 = blockIdx.x * 64;
  for (int idx = tid; idx < 1024; idx += 256) {
    int r = idx >> 4, c = idx & 15;
    int e = e0 + r; if (e >= E) e = E - 1;
    int node = (c < 8) ? ei[e] : ei[E + e];
    *(short8*)&As[r * 136 + c * 8] =
        *(const short8*)&nodeB[(size_t)node * 64 + (c & 7) * 8];
    *(short8*)&Bs[r * 136 + c * 8] = *(const short8*)&ec1T[r * 128 + c * 8];
  }
  __syncthreads();
  f32x4 acc[4] = {};
  #pragma unroll
  for (int kk = 0; kk < 4; ++kk) {
    short8 a = *(const short8*)&As[(wv * 16 + r16) * 136 + kk * 32 + g4 * 8];
    #pragma unroll
    for (int ct = 0; ct < 4; ++ct) {
      short8 b = *(const short8*)&Bs[(ct * 16 + r16) * 136 + kk * 32 + g4 * 8];
      acc[ct] = __builtin_amdgcn_mfma_f32_16x16x32_bf16(a, b, acc[ct], 0, 0, 0);
    }
  }
  float p0 = 0.f, p1 = 0.f, p2 = 0.f, p3 = 0.f;
  #pragma unroll
  for (int ct = 0; ct < 4; ++ct) {
    int c = ct * 16 + r16;
    float bb1 = b1[c], ww = w2[c];
    p0 += fmaxf(acc[ct][0] + bb1, 0.f) * ww;
    p1 += fmaxf(acc[ct][1] + bb1, 0.f) * ww;
    p2 += fmaxf(acc[ct][2] + bb1, 0.f) * ww;
    p3 += fmaxf(acc[ct][3] + bb1, 0.f) * ww;
  }
  float part[4] = {p0, p1, p2, p3};
  #pragma unroll
  for (int j = 0; j < 4; ++j) {
    float p = part[j];
    p += __shfl_xor(p, 1); p += __shfl_xor(p, 2);
    p += __shfl_xor(p, 4); p += __shfl_xor(p, 8);
    int r = e0 + wv * 16 + g4 * 4 + j;
    if (r16 == 0 && r < E) out[r] = p + b2v[0];
  }
}

extern "C" void kernel_launch(void* const* d_in, const int* in_sizes, int n_in,
                              void* d_out, int out_size, void* d_ws, size_t ws_size,
                              hipStream_t stream)
{
  const float* x     = (const float*)d_in[0];
  const float* ea    = (const float*)d_in[1];
  const float* ne_w1 = (const float*)d_in[2];
  const float* ne_b1 = (const float*)d_in[3];
  const float* ne_w2 = (const float*)d_in[4];
  const float* ne_b2 = (const float*)d_in[5];
  const float* ee_w1 = (const float*)d_in[6];
  const float* ee_b1 = (const float*)d_in[7];
  const float* ee_w2 = (const float*)d_in[8];
  const float* ee_b2 = (const float*)d_in[9];
  const float* lnc_g = (const float*)d_in[10];
  const float* lnc_b = (const float*)d_in[11];
  const float* tq_w  = (const float*)d_in[12];
  const float* tq_b  = (const float*)d_in[13];
  const float* tk_w  = (const float*)d_in[14];
  const float* tk_b  = (const float*)d_in[15];
  const float* tv_w  = (const float*)d_in[16];
  const float* tv_b  = (const float*)d_in[17];
  const float* ts_w  = (const float*)d_in[18];
  const float* ts_b  = (const float*)d_in[19];
  const float* lnt_g = (const float*)d_in[20];
  const float* lnt_b = (const float*)d_in[21];
  const float* pn_w  = (const float*)d_in[22];
  const float* pn_b  = (const float*)d_in[23];
  // d_in[24], d_in[25] = pe_w, pe_b : dead code (n_iterations=1)
  const float* ec_w1 = (const float*)d_in[26];
  const float* ec_b1 = (const float*)d_in[27];
  const float* ec_w2 = (const float*)d_in[28];
  const float* ec_b2 = (const float*)d_in[29];
  const int*   ei    = (const int*)d_in[30];

  const int N = in_sizes[0] / 6;
  const int E = in_sizes[1] / 4;
  float* out = (float*)d_out;

  char* w = (char*)d_ws;
  size_t off = 0;
  auto alloc = [&](size_t bytes) -> char* {
    char* p = w + off;
    off = (off + bytes + 255) & ~(size_t)255;
    return p;
  };
  float*  node0   = (float*)alloc((size_t)N * 64 * 4);
  float*  aggbuf  = (float*)alloc((size_t)N * 64 * 4);     // agg, later node_new
  ushort* comb    = (ushort*)alloc((size_t)N * 128 * 2);
  ushort* qkvs    = (ushort*)alloc((size_t)N * 1024 * 2);  // q|kv|s, outn over q
  ushort* nodeB   = (ushort*)alloc((size_t)N * 64 * 2);
  ushort* wqkvsT  = (ushort*)alloc(1024 * 128 * 2);
  float*  bqkvs   = (float*)alloc(1024 * 4);
  ushort* pnT     = (ushort*)alloc(64 * 256 * 2);
  ushort* ec1T    = (ushort*)alloc(64 * 128 * 2);
  ushort* ee2T    = (ushort*)alloc(64 * 64 * 2);
  int* deg      = (int*)alloc((size_t)N * 4);
  int* base     = (int*)alloc((size_t)N * 4);
  int* fillcur  = (int*)alloc((size_t)N * 4);
  int* csr_send = (int*)alloc((size_t)2 * E * 4);
  int* cursor   = (int*)alloc(256);

  float* node_new = aggbuf;  // agg dead after comb_ln

  hipMemsetAsync(aggbuf, 0, (size_t)N * 64 * 4, stream);
  hipMemsetAsync(deg, 0, (size_t)N * 4, stream);
  hipMemsetAsync(cursor, 0, 4, stream);

  // weight prep (transpose + bf16)
  prep_weights<<<(160768 + 255) / 256, 256, 0, stream>>>(
      tq_w, tk_w, tv_w, ts_w, tq_b, tk_b, tv_b, ts_b, pn_w, ec_w1, ee_w2,
      wqkvsT, bqkvs, pnT, ec1T, ee2T);
  // node encoder (fp32)
  node_encoder<<<(N + 3) / 4, 256, 0, stream>>>(x, ne_w1, ne_b1, ne_w2, ne_b2, node0, N);
  // edge path: MLP l1 + MFMA l2 + scatter + deg, one kernel
  edge_fused<<<(E + 63) / 64, 256, 0, stream>>>(
      ea, ee_w1, ee_b1, ee2T, ee_b2, ei, deg, aggbuf, E);
  // CSR build
  alloc_ranges<<<(N + 63) / 64, 64, 0, stream>>>(deg, base, fillcur, cursor, N);
  csr_fill<<<(E + 255) / 256, 256, 0, stream>>>(ei, fillcur, csr_send, E);
  // comb = LN(cat(node, agg-node)) -> bf16
  comb_ln<<<(N * 64 + 255) / 256, 256, 0, stream>>>(node0, aggbuf, lnc_g, lnc_b, comb, N);
  // fused QKVS projection: [N,128] @ [128,1024] -> bf16 qkvs (kv interleaved)
  qkvs_gemm<<<(N + 63) / 64, 256, 0, stream>>>(comb, wqkvsT, bqkvs, qkvs, N);
  // attention + skip + LN (outn over q-region of qkvs)
  attn_ln2<<<(N * 64 + 255) / 256, 256, 0, stream>>>(
      qkvs, base, deg, csr_send, lnt_g, lnt_b, N);
  // node projection + residual: outn[N,256(ld1024)] @ [256,64] + node0
  mgemm<<<dim3((N + 63) / 64, 1), 256, 0, stream>>>(
      qkvs, 1024, N, pnT, pn_b, 256, node_new, nodeB, 64, node0, 64, 0);
  // classifier: gather + GEMM + relu + dot(w2) fused
  clf_fused<<<(E + 63) / 64, 256, 0, stream>>>(
      nodeB, ei, ec1T, ec_b1, ec_w2, ec_b2, out, E);
}

// Round 4
// 335.476 us; speedup vs baseline: 2.5042x; 1.1543x over previous
//
#include <hip/hip_runtime.h>
#include <hip/hip_bf16.h>

// N=50000 nodes, E=200000 directed edges, H=4 heads, D=64, NODE_IN=6, EDGE_IN=4

typedef __attribute__((ext_vector_type(8))) short short8;          // 8 bf16
typedef __attribute__((ext_vector_type(8))) unsigned short u16x8;  // 8 bf16
typedef __attribute__((ext_vector_type(4))) float f32x4;

__device__ __forceinline__ float wave_reduce_sum(float p) {
  #pragma unroll
  for (int o = 32; o; o >>= 1) p += __shfl_xor(p, o);
  return p;
}
__device__ __forceinline__ ushort f2b(float x) {  // fp32 -> bf16 RNE
  union { float f; unsigned u; } a; a.f = x;
  unsigned r = a.u + 0x7FFF + ((a.u >> 16) & 1);
  return (ushort)(r >> 16);
}
__device__ __forceinline__ float b2f(ushort u) {
  return __uint_as_float((unsigned)u << 16);
}

// ---------------- node encoder: node0 = relu(relu(x@W1+b1)@W2+b2) (fp32) ----
__global__ __launch_bounds__(256) void node_encoder(
    const float* __restrict__ x, const float* __restrict__ w1,
    const float* __restrict__ b1, const float* __restrict__ w2,
    const float* __restrict__ b2, float* __restrict__ out, int N)
{
  __shared__ float sW2[64 * 64];
  __shared__ float sH[4][64];
  int tid = threadIdx.x;
  for (int i = tid; i < 64 * 64; i += 256) sW2[i] = w2[i];
  int wave = tid >> 6, lane = tid & 63;
  int n = blockIdx.x * 4 + wave;
  int nc = n < N ? n : (N - 1);
  float h = b1[lane];
  #pragma unroll
  for (int i = 0; i < 6; ++i) h += x[nc * 6 + i] * w1[i * 64 + lane];
  h = fmaxf(h, 0.f);
  sH[wave][lane] = h;
  __syncthreads();
  float o = b2[lane];
  #pragma unroll 8
  for (int j = 0; j < 64; ++j) o += sH[wave][j] * sW2[j * 64 + lane];
  o = fmaxf(o, 0.f);
  if (n < N) out[n * 64 + lane] = o;
}

// ------------- weight prep: transpose + cast to bf16 ------------------------
__global__ __launch_bounds__(256) void prep_weights(
    const float* __restrict__ tq_w, const float* __restrict__ tk_w,
    const float* __restrict__ tv_w, const float* __restrict__ ts_w,
    const float* __restrict__ tq_b, const float* __restrict__ tk_b,
    const float* __restrict__ tv_b, const float* __restrict__ ts_b,
    const float* __restrict__ pn_w, const float* __restrict__ ec_w1,
    const float* __restrict__ ee_w2,
    ushort* __restrict__ wqkvsT, float* __restrict__ bqkvs,
    ushort* __restrict__ pnT, ushort* __restrict__ ec1T,
    ushort* __restrict__ ee2T)
{
  int idx = blockIdx.x * 256 + threadIdx.x;
  if (idx < 131072) {                       // wqkvsT [1024][128]
    int nn = idx >> 7, k = idx & 127;
    int g = nn >> 8, c = nn & 255;
    const float* w = (g == 0) ? tq_w : (g == 1) ? tk_w : (g == 2) ? tv_w : ts_w;
    wqkvsT[idx] = f2b(w[k * 256 + c]);
  } else if (idx < 147456) {                // pnT [64][256]
    int i = idx - 131072; int c = i >> 8, k = i & 255;
    pnT[i] = f2b(pn_w[k * 64 + c]);
  } else if (idx < 155648) {                // ec1T [64][128]
    int i = idx - 147456; int c = i >> 7, k = i & 127;
    ec1T[i] = f2b(ec_w1[k * 64 + c]);
  } else if (idx < 159744) {                // ee2T [64][64]
    int i = idx - 155648; int c = i >> 6, k = i & 63;
    ee2T[i] = f2b(ee_w2[k * 64 + c]);
  } else if (idx < 160768) {                // bqkvs [1024]
    int i = idx - 159744; int g = i >> 8, c = i & 255;
    const float* b = (g == 0) ? tq_b : (g == 1) ? tk_b : (g == 2) ? tv_b : ts_b;
    bqkvs[i] = b[c];
  }
}

// ------------- degree count (int atomics, L2-resident) ----------------------
__global__ __launch_bounds__(256) void deg_count(
    const int* __restrict__ ei, int* __restrict__ deg, int E)
{
  int e = blockIdx.x * 256 + threadIdx.x;
  if (e >= E) return;
  atomicAdd(&deg[ei[e]], 1);
  atomicAdd(&deg[ei[E + e]], 1);
}

// ------------- edge encoder: MLP l1 + MFMA l2 -> f_edge bf16 (coalesced) ----
__global__ __launch_bounds__(256) void edge_enc(
    const float* __restrict__ ea, const float* __restrict__ w1,
    const float* __restrict__ b1, const ushort* __restrict__ ee2T,
    const float* __restrict__ b2, ushort* __restrict__ f, int E)
{
  __shared__ ushort As[64 * 72];
  __shared__ ushort Bs[64 * 72];
  __shared__ ushort fT[64 * 72];
  int tid = threadIdx.x;
  int wv = tid >> 6, lane = tid & 63, r16 = lane & 15, g4 = lane >> 4;
  int e0 = blockIdx.x * 64;
  // stage ee2T [64][64] -> Bs
  #pragma unroll
  for (int it = 0; it < 2; ++it) {
    int idx = tid + it * 256;
    int r = idx >> 3, c = idx & 7;
    *(short8*)&Bs[r * 72 + c * 8] = *(const short8*)&ee2T[r * 64 + c * 8];
  }
  // h = relu(ea@W1+b1), bf16, into As (thread owns col c for 16 rows)
  {
    int c = tid & 63;
    float w0 = w1[c], w1v = w1[64 + c], w2v = w1[128 + c], w3v = w1[192 + c];
    float bb = b1[c];
    int rbase = tid >> 6;
    #pragma unroll
    for (int i = 0; i < 16; ++i) {
      int r = rbase + i * 4;
      int e = e0 + r; if (e >= E) e = E - 1;
      float4 a = *(const float4*)(ea + (size_t)e * 4);
      float hv = bb + a.x * w0 + a.y * w1v + a.z * w2v + a.w * w3v;
      As[r * 72 + c] = f2b(fmaxf(hv, 0.f));
    }
  }
  __syncthreads();
  f32x4 acc[4] = {};
  #pragma unroll
  for (int kk = 0; kk < 2; ++kk) {
    short8 a = *(const short8*)&As[(wv * 16 + r16) * 72 + kk * 32 + g4 * 8];
    #pragma unroll
    for (int sc = 0; sc < 4; ++sc) {
      short8 b = *(const short8*)&Bs[(sc * 16 + r16) * 72 + kk * 32 + g4 * 8];
      acc[sc] = __builtin_amdgcn_mfma_f32_16x16x32_bf16(a, b, acc[sc], 0, 0, 0);
    }
  }
  #pragma unroll
  for (int sc = 0; sc < 4; ++sc) {
    int c = sc * 16 + r16;
    float bs = b2[c];
    #pragma unroll
    for (int j = 0; j < 4; ++j) {
      int r = wv * 16 + g4 * 4 + j;
      fT[r * 72 + c] = f2b(fmaxf(acc[sc][j] + bs, 0.f));
    }
  }
  __syncthreads();
  #pragma unroll
  for (int it = 0; it < 2; ++it) {
    int idx = tid + it * 256;
    int r = idx >> 3, c = idx & 7;
    int e = e0 + r;
    if (e < E)
      *(short8*)&f[(size_t)e * 64 + c * 8] = *(const short8*)&fT[r * 72 + c * 8];
  }
}

// ------------- CSR range allocation -----------------------------------------
__global__ __launch_bounds__(64) void alloc_ranges(
    const int* __restrict__ deg, int* __restrict__ base,
    int* __restrict__ fillcur, int* __restrict__ cursor, int N)
{
  int lane = threadIdx.x;
  int n = blockIdx.x * 64 + lane;
  int d = (n < N) ? deg[n] : 0;
  int s = d;
  #pragma unroll
  for (int o = 1; o < 64; o <<= 1) {
    int t = __shfl_up(s, o);
    if (lane >= o) s += t;
  }
  int tot = __shfl(s, 63);
  int wb = 0;
  if (lane == 63) wb = atomicAdd(cursor, tot);
  wb = __shfl(wb, 63);
  if (n < N) { base[n] = wb + s - d; fillcur[n] = wb + s - d; }
}

// ------------- CSR fill: sender node id + edge id per slot ------------------
__global__ __launch_bounds__(256) void csr_fill(
    const int* __restrict__ ei, int* __restrict__ fillcur,
    int* __restrict__ csr_send, int* __restrict__ csr_eid, int E)
{
  int e = blockIdx.x * 256 + threadIdx.x;
  if (e >= E) return;
  int a = ei[e], b = ei[E + e];
  int pa = atomicAdd(&fillcur[b], 1);
  csr_send[pa] = a; csr_eid[pa] = e;
  int pb = atomicAdd(&fillcur[a], 1);
  csr_send[pb] = b; csr_eid[pb] = e;
}

// ------------- agg gather + comb = LN(cat(node, agg-node)) (bf16 out) -------
__global__ __launch_bounds__(256) void comb_gather_ln(
    const float* __restrict__ node, const ushort* __restrict__ f_edge,
    const int* __restrict__ base, const int* __restrict__ deg,
    const int* __restrict__ csr_eid,
    const float* __restrict__ g, const float* __restrict__ b,
    ushort* __restrict__ comb, int N)
{
  int tid = blockIdx.x * 256 + threadIdx.x;
  int n = tid >> 6, lane = tid & 63;
  if (n >= N) return;
  float v0 = node[(size_t)n * 64 + lane];
  float a = 0.f;
  int b0 = base[n], dn = deg[n];
  int j = 0;
  for (; j + 1 < dn; j += 2) {
    int e0 = csr_eid[b0 + j], e1 = csr_eid[b0 + j + 1];
    a += b2f(f_edge[(size_t)e0 * 64 + lane]);
    a += b2f(f_edge[(size_t)e1 * 64 + lane]);
  }
  if (j < dn) a += b2f(f_edge[(size_t)csr_eid[b0 + j] * 64 + lane]);
  float v1 = a - v0;
  float s = wave_reduce_sum(v0 + v1);
  float ss = wave_reduce_sum(v0 * v0 + v1 * v1);
  float mean = s * (1.f / 128.f);
  float var = ss * (1.f / 128.f) - mean * mean;
  float rstd = rsqrtf(var + 1e-5f);
  comb[(size_t)n * 128 + lane]      = f2b((v0 - mean) * rstd * g[lane] + b[lane]);
  comb[(size_t)n * 128 + 64 + lane] = f2b((v1 - mean) * rstd * g[64 + lane] + b[64 + lane]);
}

// ------------- fused QKVS GEMM: A staged once, loop 16 col tiles ------------
// Output columns permuted so k/v for one lane-slot are contiguous 16B:
// [0,256)=q | [256,768)=kv interleaved | [768,1024)=s
__global__ __launch_bounds__(256) void qkvs_gemm(
    const ushort* __restrict__ comb, const ushort* __restrict__ wqkvsT,
    const float* __restrict__ bias, ushort* __restrict__ qkvs, int N)
{
  __shared__ ushort As[64 * 136];
  __shared__ ushort Bs[2][64 * 136];
  int tid = threadIdx.x;
  int wv = tid >> 6, lane = tid & 63, r16 = lane & 15, g4 = lane >> 4;
  int row0 = blockIdx.x * 64;
  #pragma unroll
  for (int it = 0; it < 4; ++it) {
    int idx = tid + it * 256;
    int r = idx >> 4, c = idx & 15;
    int gr = row0 + r; if (gr >= N) gr = N - 1;
    *(short8*)&As[r * 136 + c * 8] = *(const short8*)&comb[(size_t)gr * 128 + c * 8];
    *(short8*)&Bs[0][r * 136 + c * 8] = *(const short8*)&wqkvsT[(size_t)r * 128 + c * 8];
  }
  for (int ct = 0; ct < 16; ++ct) {
    __syncthreads();
    if (ct < 15) {
      #pragma unroll
      for (int it = 0; it < 4; ++it) {
        int idx = tid + it * 256;
        int r = idx >> 4, c = idx & 15;
        *(short8*)&Bs[(ct + 1) & 1][r * 136 + c * 8] =
            *(const short8*)&wqkvsT[(size_t)((ct + 1) * 64 + r) * 128 + c * 8];
      }
    }
    f32x4 acc[4] = {};
    #pragma unroll
    for (int kk = 0; kk < 4; ++kk) {
      short8 a = *(const short8*)&As[(wv * 16 + r16) * 136 + kk * 32 + g4 * 8];
      #pragma unroll
      for (int sc = 0; sc < 4; ++sc) {
        short8 b = *(const short8*)&Bs[ct & 1][(sc * 16 + r16) * 136 + kk * 32 + g4 * 8];
        acc[sc] = __builtin_amdgcn_mfma_f32_16x16x32_bf16(a, b, acc[sc], 0, 0, 0);
      }
    }
    #pragma unroll
    for (int sc = 0; sc < 4; ++sc) {
      int c = ct * 64 + sc * 16 + r16;
      int p;
      if (c < 256) p = c;
      else if (c < 512) { int d = c - 256; p = 256 + (d >> 6) * 128 + ((d & 63) >> 2) * 8 + (d & 3); }
      else if (c < 768) { int d = c - 512; p = 256 + (d >> 6) * 128 + ((d & 63) >> 2) * 8 + 4 + (d & 3); }
      else p = c;
      float bs = bias[c];
      #pragma unroll
      for (int j = 0; j < 4; ++j) {
        int r = row0 + wv * 16 + g4 * 4 + j;
        if (r < N) qkvs[(size_t)r * 1024 + p] = f2b(acc[sc][j] + bs);
      }
    }
  }
}

// ------------- generic bf16 MFMA GEMM (used for proj only) ------------------
__global__ __launch_bounds__(256) void mgemm(
    const ushort* __restrict__ A, int lda, int M,
    const ushort* __restrict__ BT, const float* __restrict__ bias, int K,
    float* __restrict__ outF, ushort* __restrict__ outB, int ldo,
    const float* __restrict__ res, int ldres, int doRelu)
{
  __shared__ ushort As[64 * 136];
  __shared__ ushort Bs[64 * 136];
  int tid = threadIdx.x;
  int wv = tid >> 6, lane = tid & 63;
  int r16 = lane & 15, g4 = lane >> 4;
  int row0 = blockIdx.x * 64, col0 = blockIdx.y * 64;
  f32x4 acc[4] = {};
  for (int k0 = 0; k0 < K; k0 += 128) {
    int BK = K - k0; if (BK > 128) BK = 128;
    int csh = (BK == 64) ? 3 : 4;
    int cmask = (1 << csh) - 1;
    int tot = 64 << csh;
    for (int idx = tid; idx < tot; idx += 256) {
      int r = idx >> csh, c = idx & cmask;
      int gr = row0 + r; if (gr >= M) gr = M - 1;
      *(short8*)&As[r * 136 + c * 8] =
          *(const short8*)&A[(size_t)gr * lda + k0 + c * 8];
      *(short8*)&Bs[r * 136 + c * 8] =
          *(const short8*)&BT[(size_t)(col0 + r) * K + k0 + c * 8];
    }
    __syncthreads();
    int ks = BK >> 5;
    for (int kk = 0; kk < ks; ++kk) {
      short8 a = *(const short8*)&As[(wv * 16 + r16) * 136 + kk * 32 + g4 * 8];
      #pragma unroll
      for (int ct = 0; ct < 4; ++ct) {
        short8 b = *(const short8*)&Bs[(ct * 16 + r16) * 136 + kk * 32 + g4 * 8];
        acc[ct] = __builtin_amdgcn_mfma_f32_16x16x32_bf16(a, b, acc[ct], 0, 0, 0);
      }
    }
    __syncthreads();
  }
  #pragma unroll
  for (int ct = 0; ct < 4; ++ct) {
    int c = col0 + ct * 16 + r16;
    float bs = bias[c];
    #pragma unroll
    for (int j = 0; j < 4; ++j) {
      int r = row0 + wv * 16 + g4 * 4 + j;
      if (r >= M) continue;
      float vv = acc[ct][j] + bs;
      if (doRelu) vv = fmaxf(vv, 0.f);
      if (res) vv += res[(size_t)r * ldres + c];
      if (outF) outF[(size_t)r * ldo + c] = vv;
      if (outB) outB[(size_t)r * ldo + c] = f2b(vv);
    }
  }
}

// ------------- attention + skip + LN; kv read as one 16B load, unroll x2 ----
__global__ __launch_bounds__(256) void attn_ln2(
    ushort* __restrict__ qkvs, const int* __restrict__ base,
    const int* __restrict__ deg, const int* __restrict__ csr_send,
    const float* __restrict__ g, const float* __restrict__ bb, int N)
{
  int tid = blockIdx.x * 256 + threadIdx.x;
  int n = tid >> 6, lane = tid & 63;
  if (n >= N) return;
  int dbase = (lane >> 4) * 64 + (lane & 15) * 4;              // head*64 + slot
  int kvoff = 256 + (lane >> 4) * 128 + (lane & 15) * 8;       // interleaved kv
  ushort4 qu = *(const ushort4*)(qkvs + (size_t)n * 1024 + dbase);
  float q0 = b2f(qu.x), q1 = b2f(qu.y), q2 = b2f(qu.z), q3 = b2f(qu.w);
  float m = -1e30f, l = 0.f, a0 = 0.f, a1 = 0.f, a2 = 0.f, a3 = 0.f;
  int b0 = base[n], dn = deg[n];
  int j = 0;
  for (; j + 1 < dn; j += 2) {
    int s0 = csr_send[b0 + j], s1 = csr_send[b0 + j + 1];
    u16x8 kvA = *(const u16x8*)(qkvs + (size_t)s0 * 1024 + kvoff);
    u16x8 kvB = *(const u16x8*)(qkvs + (size_t)s1 * 1024 + kvoff);
    float pA = q0 * b2f((ushort)kvA[0]) + q1 * b2f((ushort)kvA[1]) +
               q2 * b2f((ushort)kvA[2]) + q3 * b2f((ushort)kvA[3]);
    float pB = q0 * b2f((ushort)kvB[0]) + q1 * b2f((ushort)kvB[1]) +
               q2 * b2f((ushort)kvB[2]) + q3 * b2f((ushort)kvB[3]);
    pA += __shfl_xor(pA, 1); pB += __shfl_xor(pB, 1);
    pA += __shfl_xor(pA, 2); pB += __shfl_xor(pB, 2);
    pA += __shfl_xor(pA, 4); pB += __shfl_xor(pB, 4);
    pA += __shfl_xor(pA, 8); pB += __shfl_xor(pB, 8);
    pA *= 0.125f; pB *= 0.125f;
    float mn = fmaxf(m, fmaxf(pA, pB));
    float e1 = __expf(m - mn);
    float peA = __expf(pA - mn), peB = __expf(pB - mn);
    l = l * e1 + peA + peB;
    a0 = a0 * e1 + peA * b2f((ushort)kvA[4]) + peB * b2f((ushort)kvB[4]);
    a1 = a1 * e1 + peA * b2f((ushort)kvA[5]) + peB * b2f((ushort)kvB[5]);
    a2 = a2 * e1 + peA * b2f((ushort)kvA[6]) + peB * b2f((ushort)kvB[6]);
    a3 = a3 * e1 + peA * b2f((ushort)kvA[7]) + peB * b2f((ushort)kvB[7]);
    m = mn;
  }
  if (j < dn) {
    int s = csr_send[b0 + j];
    u16x8 kv = *(const u16x8*)(qkvs + (size_t)s * 1024 + kvoff);
    float p = q0 * b2f((ushort)kv[0]) + q1 * b2f((ushort)kv[1]) +
              q2 * b2f((ushort)kv[2]) + q3 * b2f((ushort)kv[3]);
    p += __shfl_xor(p, 1); p += __shfl_xor(p, 2);
    p += __shfl_xor(p, 4); p += __shfl_xor(p, 8);
    p *= 0.125f;
    float mn = fmaxf(m, p);
    float e1 = __expf(m - mn), pe = __expf(p - mn);
    l = l * e1 + pe;
    a0 = a0 * e1 + pe * b2f((ushort)kv[4]);
    a1 = a1 * e1 + pe * b2f((ushort)kv[5]);
    a2 = a2 * e1 + pe * b2f((ushort)kv[6]);
    a3 = a3 * e1 + pe * b2f((ushort)kv[7]);
    m = mn;
  }
  ushort4 su = *(const ushort4*)(qkvs + (size_t)n * 1024 + 768 + dbase);
  float rl = 1.f / (l + 1e-16f);
  float y0 = a0 * rl + b2f(su.x), y1 = a1 * rl + b2f(su.y);
  float y2 = a2 * rl + b2f(su.z), y3 = a3 * rl + b2f(su.w);
  float s1 = wave_reduce_sum(y0 + y1 + y2 + y3);
  float s2 = wave_reduce_sum(y0 * y0 + y1 * y1 + y2 * y2 + y3 * y3);
  float mean = s1 * (1.f / 256.f);
  float var = s2 * (1.f / 256.f) - mean * mean;
  float rstd = rsqrtf(var + 1e-5f);
  ushort4 o;
  o.x = f2b((y0 - mean) * rstd * g[dbase + 0] + bb[dbase + 0]);
  o.y = f2b((y1 - mean) * rstd * g[dbase + 1] + bb[dbase + 1]);
  o.z = f2b((y2 - mean) * rstd * g[dbase + 2] + bb[dbase + 2]);
  o.w = f2b((y3 - mean) * rstd * g[dbase + 3] + bb[dbase + 3]);
  *(ushort4*)(qkvs + (size_t)n * 1024 + dbase) = o;
}

// ------------- classifier, fully fused: gather + GEMM + relu + dot(w2) ------
__global__ __launch_bounds__(256) void clf_fused(
    const ushort* __restrict__ nodeB, const int* __restrict__ ei,
    const ushort* __restrict__ ec1T, const float* __restrict__ b1,
    const float* __restrict__ w2, const float* __restrict__ b2v,
    float* __restrict__ out, int E)
{
  __shared__ ushort As[64 * 136];
  __shared__ ushort Bs[64 * 136];
  int tid = threadIdx.x;
  int wv = tid >> 6, lane = tid & 63;
  int r16 = lane & 15, g4 = lane >> 4;
  int e0 = blockIdx.x * 64;
  for (int idx = tid; idx < 1024; idx += 256) {
    int r = idx >> 4, c = idx & 15;
    int e = e0 + r; if (e >= E) e = E - 1;
    int node = (c < 8) ? ei[e] : ei[E + e];
    *(short8*)&As[r * 136 + c * 8] =
        *(const short8*)&nodeB[(size_t)node * 64 + (c & 7) * 8];
    *(short8*)&Bs[r * 136 + c * 8] = *(const short8*)&ec1T[r * 128 + c * 8];
  }
  __syncthreads();
  f32x4 acc[4] = {};
  #pragma unroll
  for (int kk = 0; kk < 4; ++kk) {
    short8 a = *(const short8*)&As[(wv * 16 + r16) * 136 + kk * 32 + g4 * 8];
    #pragma unroll
    for (int ct = 0; ct < 4; ++ct) {
      short8 b = *(const short8*)&Bs[(ct * 16 + r16) * 136 + kk * 32 + g4 * 8];
      acc[ct] = __builtin_amdgcn_mfma_f32_16x16x32_bf16(a, b, acc[ct], 0, 0, 0);
    }
  }
  float p0 = 0.f, p1 = 0.f, p2 = 0.f, p3 = 0.f;
  #pragma unroll
  for (int ct = 0; ct < 4; ++ct) {
    int c = ct * 16 + r16;
    float bb1 = b1[c], ww = w2[c];
    p0 += fmaxf(acc[ct][0] + bb1, 0.f) * ww;
    p1 += fmaxf(acc[ct][1] + bb1, 0.f) * ww;
    p2 += fmaxf(acc[ct][2] + bb1, 0.f) * ww;
    p3 += fmaxf(acc[ct][3] + bb1, 0.f) * ww;
  }
  float part[4] = {p0, p1, p2, p3};
  #pragma unroll
  for (int j = 0; j < 4; ++j) {
    float p = part[j];
    p += __shfl_xor(p, 1); p += __shfl_xor(p, 2);
    p += __shfl_xor(p, 4); p += __shfl_xor(p, 8);
    int r = e0 + wv * 16 + g4 * 4 + j;
    if (r16 == 0 && r < E) out[r] = p + b2v[0];
  }
}

extern "C" void kernel_launch(void* const* d_in, const int* in_sizes, int n_in,
                              void* d_out, int out_size, void* d_ws, size_t ws_size,
                              hipStream_t stream)
{
  const float* x     = (const float*)d_in[0];
  const float* ea    = (const float*)d_in[1];
  const float* ne_w1 = (const float*)d_in[2];
  const float* ne_b1 = (const float*)d_in[3];
  const float* ne_w2 = (const float*)d_in[4];
  const float* ne_b2 = (const float*)d_in[5];
  const float* ee_w1 = (const float*)d_in[6];
  const float* ee_b1 = (const float*)d_in[7];
  const float* ee_w2 = (const float*)d_in[8];
  const float* ee_b2 = (const float*)d_in[9];
  const float* lnc_g = (const float*)d_in[10];
  const float* lnc_b = (const float*)d_in[11];
  const float* tq_w  = (const float*)d_in[12];
  const float* tq_b  = (const float*)d_in[13];
  const float* tk_w  = (const float*)d_in[14];
  const float* tk_b  = (const float*)d_in[15];
  const float* tv_w  = (const float*)d_in[16];
  const float* tv_b  = (const float*)d_in[17];
  const float* ts_w  = (const float*)d_in[18];
  const float* ts_b  = (const float*)d_in[19];
  const float* lnt_g = (const float*)d_in[20];
  const float* lnt_b = (const float*)d_in[21];
  const float* pn_w  = (const float*)d_in[22];
  const float* pn_b  = (const float*)d_in[23];
  // d_in[24], d_in[25] = pe_w, pe_b : dead code (n_iterations=1)
  const float* ec_w1 = (const float*)d_in[26];
  const float* ec_b1 = (const float*)d_in[27];
  const float* ec_w2 = (const float*)d_in[28];
  const float* ec_b2 = (const float*)d_in[29];
  const int*   ei    = (const int*)d_in[30];

  const int N = in_sizes[0] / 6;
  const int E = in_sizes[1] / 4;
  float* out = (float*)d_out;

  char* w = (char*)d_ws;
  size_t off = 0;
  auto alloc = [&](size_t bytes) -> char* {
    char* p = w + off;
    off = (off + bytes + 255) & ~(size_t)255;
    return p;
  };
  float*  node0   = (float*)alloc((size_t)N * 64 * 4);
  ushort* comb    = (ushort*)alloc((size_t)N * 128 * 2);
  ushort* qkvs    = (ushort*)alloc((size_t)N * 1024 * 2);  // q|kv|s, outn over q
  ushort* f_edge  = (ushort*)alloc((size_t)E * 64 * 2);    // later free
  ushort* nodeB   = (ushort*)alloc((size_t)N * 64 * 2);
  ushort* wqkvsT  = (ushort*)alloc(1024 * 128 * 2);
  float*  bqkvs   = (float*)alloc(1024 * 4);
  ushort* pnT     = (ushort*)alloc(64 * 256 * 2);
  ushort* ec1T    = (ushort*)alloc(64 * 128 * 2);
  ushort* ee2T    = (ushort*)alloc(64 * 64 * 2);
  int* deg      = (int*)alloc((size_t)N * 4);
  int* base     = (int*)alloc((size_t)N * 4);
  int* fillcur  = (int*)alloc((size_t)N * 4);
  int* csr_send = (int*)alloc((size_t)2 * E * 4);
  int* csr_eid  = (int*)alloc((size_t)2 * E * 4);
  int* cursor   = (int*)alloc(256);

  hipMemsetAsync(deg, 0, (size_t)N * 4, stream);
  hipMemsetAsync(cursor, 0, 4, stream);

  // weight prep (transpose + bf16)
  prep_weights<<<(160768 + 255) / 256, 256, 0, stream>>>(
      tq_w, tk_w, tv_w, ts_w, tq_b, tk_b, tv_b, ts_b, pn_w, ec_w1, ee_w2,
      wqkvsT, bqkvs, pnT, ec1T, ee2T);
  // node encoder (fp32)
  node_encoder<<<(N + 3) / 4, 256, 0, stream>>>(x, ne_w1, ne_b1, ne_w2, ne_b2, node0, N);
  // degree count
  deg_count<<<(E + 255) / 256, 256, 0, stream>>>(ei, deg, E);
  // edge encoder -> f_edge bf16
  edge_enc<<<(E + 63) / 64, 256, 0, stream>>>(ea, ee_w1, ee_b1, ee2T, ee_b2, f_edge, E);
  // CSR build (sender node + edge id)
  alloc_ranges<<<(N + 63) / 64, 64, 0, stream>>>(deg, base, fillcur, cursor, N);
  csr_fill<<<(E + 255) / 256, 256, 0, stream>>>(ei, fillcur, csr_send, csr_eid, E);
  // agg gather + comb LN -> bf16
  comb_gather_ln<<<(N * 64 + 255) / 256, 256, 0, stream>>>(
      node0, f_edge, base, deg, csr_eid, lnc_g, lnc_b, comb, N);
  // fused QKVS projection: [N,128] @ [128,1024] -> bf16 qkvs (kv interleaved)
  qkvs_gemm<<<(N + 63) / 64, 256, 0, stream>>>(comb, wqkvsT, bqkvs, qkvs, N);
  // attention + skip + LN (outn over q-region of qkvs)
  attn_ln2<<<(N * 64 + 255) / 256, 256, 0, stream>>>(
      qkvs, base, deg, csr_send, lnt_g, lnt_b, N);
  // node projection + residual -> nodeB (bf16 only; fp32 copy unused)
  mgemm<<<dim3((N + 63) / 64, 1), 256, 0, stream>>>(
      qkvs, 1024, N, pnT, pn_b, 256, nullptr, nodeB, 64, node0, 64, 0);
  // classifier: gather + GEMM + relu + dot(w2) fused
  clf_fused<<<(E + 63) / 64, 256, 0, stream>>>(
      nodeB, ei, ec1T, ec_b1, ec_w2, ec_b2, out, E);
}

// Round 5
// 287.160 us; speedup vs baseline: 2.9255x; 1.1683x over previous
//
#include <hip/hip_runtime.h>
#include <hip/hip_bf16.h>

// N=50000 nodes, E=200000 directed edges, H=4 heads, D=64, NODE_IN=6, EDGE_IN=4

typedef __attribute__((ext_vector_type(8))) short short8;          // 8 bf16
typedef __attribute__((ext_vector_type(8))) unsigned short u16x8;  // 8 bf16
typedef __attribute__((ext_vector_type(4))) float f32x4;

__device__ __forceinline__ float wave_reduce_sum(float p) {
  #pragma unroll
  for (int o = 32; o; o >>= 1) p += __shfl_xor(p, o);
  return p;
}
__device__ __forceinline__ ushort f2b(float x) {  // fp32 -> bf16 RNE
  union { float f; unsigned u; } a; a.f = x;
  unsigned r = a.u + 0x7FFF + ((a.u >> 16) & 1);
  return (ushort)(r >> 16);
}
__device__ __forceinline__ float b2f(ushort u) {
  return __uint_as_float((unsigned)u << 16);
}

// ---------------- node encoder: node0 = relu(relu(x@W1+b1)@W2+b2) (fp32) ----
__global__ __launch_bounds__(256) void node_encoder(
    const float* __restrict__ x, const float* __restrict__ w1,
    const float* __restrict__ b1, const float* __restrict__ w2,
    const float* __restrict__ b2, float* __restrict__ out, int N)
{
  __shared__ float sW2[64 * 64];
  __shared__ float sH[4][64];
  int tid = threadIdx.x;
  for (int i = tid; i < 64 * 64; i += 256) sW2[i] = w2[i];
  int wave = tid >> 6, lane = tid & 63;
  int n = blockIdx.x * 4 + wave;
  int nc = n < N ? n : (N - 1);
  float h = b1[lane];
  #pragma unroll
  for (int i = 0; i < 6; ++i) h += x[nc * 6 + i] * w1[i * 64 + lane];
  h = fmaxf(h, 0.f);
  sH[wave][lane] = h;
  __syncthreads();
  float o = b2[lane];
  #pragma unroll 8
  for (int j = 0; j < 64; ++j) o += sH[wave][j] * sW2[j * 64 + lane];
  o = fmaxf(o, 0.f);
  if (n < N) out[n * 64 + lane] = o;
}

// ------------- weight prep: transpose + cast + kv-interleave permutation ----
// qkvs column p (in [0,1024)) maps to source (matrix g, col cc):
//   p<256: q col p | p in [256,768): head=(p-256)>>7, w=(p-256)&127,
//     slot=w>>3, o=w&7 -> o<4 ? k col head*64+slot*4+o : v col head*64+slot*4+o-4
//   p>=768: s col p-768
__global__ __launch_bounds__(256) void prep_weights(
    const float* __restrict__ tq_w, const float* __restrict__ tk_w,
    const float* __restrict__ tv_w, const float* __restrict__ ts_w,
    const float* __restrict__ tq_b, const float* __restrict__ tk_b,
    const float* __restrict__ tv_b, const float* __restrict__ ts_b,
    const float* __restrict__ pn_w, const float* __restrict__ ec_w1,
    const float* __restrict__ ee_w2,
    ushort* __restrict__ wqkvsT, float* __restrict__ bqkvs,
    ushort* __restrict__ pnT, ushort* __restrict__ ec1T,
    ushort* __restrict__ ee2T)
{
  int idx = blockIdx.x * 256 + threadIdx.x;
  if (idx < 131072) {                       // wqkvsT [1024][128], permuted cols
    int p = idx >> 7, k = idx & 127;
    int g, cc;
    if (p < 256) { g = 0; cc = p; }
    else if (p < 768) {
      int d2 = p - 256; int head = d2 >> 7; int ww = d2 & 127;
      int slot = ww >> 3; int o = ww & 7;
      if (o < 4) { g = 1; cc = head * 64 + slot * 4 + o; }
      else       { g = 2; cc = head * 64 + slot * 4 + o - 4; }
    } else { g = 3; cc = p - 768; }
    const float* w = (g == 0) ? tq_w : (g == 1) ? tk_w : (g == 2) ? tv_w : ts_w;
    wqkvsT[idx] = f2b(w[k * 256 + cc]);
  } else if (idx < 147456) {                // pnT [64][256]
    int i = idx - 131072; int c = i >> 8, k = i & 255;
    pnT[i] = f2b(pn_w[k * 64 + c]);
  } else if (idx < 155648) {                // ec1T [64][128]
    int i = idx - 147456; int c = i >> 7, k = i & 127;
    ec1T[i] = f2b(ec_w1[k * 64 + c]);
  } else if (idx < 159744) {                // ee2T [64][64]
    int i = idx - 155648; int c = i >> 6, k = i & 63;
    ee2T[i] = f2b(ee_w2[k * 64 + c]);
  } else if (idx < 160768) {                // bqkvs [1024], permuted
    int p = idx - 159744;
    int g, cc;
    if (p < 256) { g = 0; cc = p; }
    else if (p < 768) {
      int d2 = p - 256; int head = d2 >> 7; int ww = d2 & 127;
      int slot = ww >> 3; int o = ww & 7;
      if (o < 4) { g = 1; cc = head * 64 + slot * 4 + o; }
      else       { g = 2; cc = head * 64 + slot * 4 + o - 4; }
    } else { g = 3; cc = p - 768; }
    const float* b = (g == 0) ? tq_b : (g == 1) ? tk_b : (g == 2) ? tv_b : ts_b;
    bqkvs[p] = b[cc];
  }
}

// ------------- degree count (int atomics, L2-resident) ----------------------
__global__ __launch_bounds__(256) void deg_count(
    const int* __restrict__ ei, int* __restrict__ deg, int E)
{
  int e = blockIdx.x * 256 + threadIdx.x;
  if (e >= E) return;
  atomicAdd(&deg[ei[e]], 1);
  atomicAdd(&deg[ei[E + e]], 1);
}

// ------------- edge encoder: MLP l1 + MFMA l2 -> f_edge bf16 (coalesced) ----
__global__ __launch_bounds__(256) void edge_enc(
    const float* __restrict__ ea, const float* __restrict__ w1,
    const float* __restrict__ b1, const ushort* __restrict__ ee2T,
    const float* __restrict__ b2, ushort* __restrict__ f, int E)
{
  __shared__ ushort As[64 * 72];
  __shared__ ushort Bs[64 * 72];
  __shared__ ushort fT[64 * 72];
  int tid = threadIdx.x;
  int wv = tid >> 6, lane = tid & 63, r16 = lane & 15, g4 = lane >> 4;
  int e0 = blockIdx.x * 64;
  // stage ee2T [64][64] -> Bs
  #pragma unroll
  for (int it = 0; it < 2; ++it) {
    int idx = tid + it * 256;
    int r = idx >> 3, c = idx & 7;
    *(short8*)&Bs[r * 72 + c * 8] = *(const short8*)&ee2T[r * 64 + c * 8];
  }
  // h = relu(ea@W1+b1), bf16, into As (thread owns col c for 16 rows)
  {
    int c = tid & 63;
    float w0 = w1[c], w1v = w1[64 + c], w2v = w1[128 + c], w3v = w1[192 + c];
    float bb = b1[c];
    int rbase = tid >> 6;
    #pragma unroll
    for (int i = 0; i < 16; ++i) {
      int r = rbase + i * 4;
      int e = e0 + r; if (e >= E) e = E - 1;
      float4 a = *(const float4*)(ea + (size_t)e * 4);
      float hv = bb + a.x * w0 + a.y * w1v + a.z * w2v + a.w * w3v;
      As[r * 72 + c] = f2b(fmaxf(hv, 0.f));
    }
  }
  __syncthreads();
  f32x4 acc[4] = {};
  #pragma unroll
  for (int kk = 0; kk < 2; ++kk) {
    short8 a = *(const short8*)&As[(wv * 16 + r16) * 72 + kk * 32 + g4 * 8];
    #pragma unroll
    for (int sc = 0; sc < 4; ++sc) {
      short8 b = *(const short8*)&Bs[(sc * 16 + r16) * 72 + kk * 32 + g4 * 8];
      acc[sc] = __builtin_amdgcn_mfma_f32_16x16x32_bf16(a, b, acc[sc], 0, 0, 0);
    }
  }
  #pragma unroll
  for (int sc = 0; sc < 4; ++sc) {
    int c = sc * 16 + r16;
    float bs = b2[c];
    #pragma unroll
    for (int j = 0; j < 4; ++j) {
      int r = wv * 16 + g4 * 4 + j;
      fT[r * 72 + c] = f2b(fmaxf(acc[sc][j] + bs, 0.f));
    }
  }
  __syncthreads();
  #pragma unroll
  for (int it = 0; it < 2; ++it) {
    int idx = tid + it * 256;
    int r = idx >> 3, c = idx & 7;
    int e = e0 + r;
    if (e < E)
      *(short8*)&f[(size_t)e * 64 + c * 8] = *(const short8*)&fT[r * 72 + c * 8];
  }
}

// ------------- CSR range allocation -----------------------------------------
__global__ __launch_bounds__(64) void alloc_ranges(
    const int* __restrict__ deg, int* __restrict__ base,
    int* __restrict__ fillcur, int* __restrict__ cursor, int N)
{
  int lane = threadIdx.x;
  int n = blockIdx.x * 64 + lane;
  int d = (n < N) ? deg[n] : 0;
  int s = d;
  #pragma unroll
  for (int o = 1; o < 64; o <<= 1) {
    int t = __shfl_up(s, o);
    if (lane >= o) s += t;
  }
  int tot = __shfl(s, 63);
  int wb = 0;
  if (lane == 63) wb = atomicAdd(cursor, tot);
  wb = __shfl(wb, 63);
  if (n < N) { base[n] = wb + s - d; fillcur[n] = wb + s - d; }
}

// ------------- CSR fill: sender node id + edge id per slot ------------------
__global__ __launch_bounds__(256) void csr_fill(
    const int* __restrict__ ei, int* __restrict__ fillcur,
    int* __restrict__ csr_send, int* __restrict__ csr_eid, int E)
{
  int e = blockIdx.x * 256 + threadIdx.x;
  if (e >= E) return;
  int a = ei[e], b = ei[E + e];
  int pa = atomicAdd(&fillcur[b], 1);
  csr_send[pa] = a; csr_eid[pa] = e;
  int pb = atomicAdd(&fillcur[a], 1);
  csr_send[pb] = b; csr_eid[pb] = e;
}

// ------------- agg gather + comb = LN(cat(node, agg-node)) (bf16 out) -------
__global__ __launch_bounds__(256) void comb_gather_ln(
    const float* __restrict__ node, const ushort* __restrict__ f_edge,
    const int* __restrict__ base, const int* __restrict__ deg,
    const int* __restrict__ csr_eid,
    const float* __restrict__ g, const float* __restrict__ b,
    ushort* __restrict__ comb, int N)
{
  int tid = blockIdx.x * 256 + threadIdx.x;
  int n = tid >> 6, lane = tid & 63;
  if (n >= N) return;
  float v0 = node[(size_t)n * 64 + lane];
  float a = 0.f;
  int b0 = base[n], dn = deg[n];
  int j = 0;
  for (; j + 1 < dn; j += 2) {
    int e0 = csr_eid[b0 + j], e1 = csr_eid[b0 + j + 1];
    a += b2f(f_edge[(size_t)e0 * 64 + lane]);
    a += b2f(f_edge[(size_t)e1 * 64 + lane]);
  }
  if (j < dn) a += b2f(f_edge[(size_t)csr_eid[b0 + j] * 64 + lane]);
  float v1 = a - v0;
  float s = wave_reduce_sum(v0 + v1);
  float ss = wave_reduce_sum(v0 * v0 + v1 * v1);
  float mean = s * (1.f / 128.f);
  float var = ss * (1.f / 128.f) - mean * mean;
  float rstd = rsqrtf(var + 1e-5f);
  comb[(size_t)n * 128 + lane]      = f2b((v0 - mean) * rstd * g[lane] + b[lane]);
  comb[(size_t)n * 128 + 64 + lane] = f2b((v1 - mean) * rstd * g[64 + lane] + b[64 + lane]);
}

// ------------- fused QKVS GEMM: A staged once, 16 col tiles -----------------
// Weights pre-permuted -> output columns contiguous. Register-prefetch B,
// LDS-staged bf16 epilogue with short8 coalesced stores.
__global__ __launch_bounds__(256) void qkvs_gemm(
    const ushort* __restrict__ comb, const ushort* __restrict__ wqkvsT,
    const float* __restrict__ bias, ushort* __restrict__ qkvs, int N)
{
  __shared__ ushort As[64 * 136];
  __shared__ ushort Bs[64 * 136];
  __shared__ ushort Os[64 * 68];
  int tid = threadIdx.x;
  int wv = tid >> 6, lane = tid & 63, r16 = lane & 15, g4 = lane >> 4;
  int row0 = blockIdx.x * 64;
  #pragma unroll
  for (int it = 0; it < 4; ++it) {
    int idx = tid + it * 256;
    int r = idx >> 4, c = idx & 15;
    int gr = row0 + r; if (gr >= N) gr = N - 1;
    *(short8*)&As[r * 136 + c * 8] = *(const short8*)&comb[(size_t)gr * 128 + c * 8];
    *(short8*)&Bs[r * 136 + c * 8] = *(const short8*)&wqkvsT[(size_t)r * 128 + c * 8];
  }
  __syncthreads();
  for (int ct = 0; ct < 16; ++ct) {
    // prefetch next B tile to registers
    short8 pf[4];
    if (ct < 15) {
      #pragma unroll
      for (int it = 0; it < 4; ++it) {
        int idx = tid + it * 256;
        int r = idx >> 4, c = idx & 15;
        pf[it] = *(const short8*)&wqkvsT[(size_t)((ct + 1) * 64 + r) * 128 + c * 8];
      }
    }
    f32x4 acc[4] = {};
    #pragma unroll
    for (int kk = 0; kk < 4; ++kk) {
      short8 a = *(const short8*)&As[(wv * 16 + r16) * 136 + kk * 32 + g4 * 8];
      #pragma unroll
      for (int sc = 0; sc < 4; ++sc) {
        short8 b = *(const short8*)&Bs[(sc * 16 + r16) * 136 + kk * 32 + g4 * 8];
        acc[sc] = __builtin_amdgcn_mfma_f32_16x16x32_bf16(a, b, acc[sc], 0, 0, 0);
      }
    }
    __syncthreads();   // done reading Bs; prev Os stores done
    if (ct < 15) {
      #pragma unroll
      for (int it = 0; it < 4; ++it) {
        int idx = tid + it * 256;
        int r = idx >> 4, c = idx & 15;
        *(short8*)&Bs[r * 136 + c * 8] = pf[it];
      }
    }
    #pragma unroll
    for (int sc = 0; sc < 4; ++sc) {
      float bs = bias[ct * 64 + sc * 16 + r16];
      #pragma unroll
      for (int j = 0; j < 4; ++j)
        Os[(wv * 16 + g4 * 4 + j) * 68 + sc * 16 + r16] = f2b(acc[sc][j] + bs);
    }
    __syncthreads();   // Os filled, Bs refilled
    #pragma unroll
    for (int it = 0; it < 2; ++it) {
      int idx = tid + it * 256;
      int r = idx >> 3, ch = idx & 7;
      int gr = row0 + r;
      if (gr < N)
        *(short8*)&qkvs[(size_t)gr * 1024 + ct * 64 + ch * 8] =
            *(const short8*)&Os[r * 68 + ch * 8];
    }
  }
}

// ------------- generic bf16 MFMA GEMM (proj) with staged bf16 stores --------
__global__ __launch_bounds__(256) void mgemm(
    const ushort* __restrict__ A, int lda, int M,
    const ushort* __restrict__ BT, const float* __restrict__ bias, int K,
    ushort* __restrict__ outB, int ldo,
    const float* __restrict__ res, int ldres, int doRelu)
{
  __shared__ ushort As[64 * 136];
  __shared__ ushort Bs[64 * 136];
  __shared__ ushort Os[64 * 68];
  int tid = threadIdx.x;
  int wv = tid >> 6, lane = tid & 63;
  int r16 = lane & 15, g4 = lane >> 4;
  int row0 = blockIdx.x * 64, col0 = blockIdx.y * 64;
  f32x4 acc[4] = {};
  for (int k0 = 0; k0 < K; k0 += 128) {
    int BK = K - k0; if (BK > 128) BK = 128;
    int csh = (BK == 64) ? 3 : 4;
    int cmask = (1 << csh) - 1;
    int tot = 64 << csh;
    for (int idx = tid; idx < tot; idx += 256) {
      int r = idx >> csh, c = idx & cmask;
      int gr = row0 + r; if (gr >= M) gr = M - 1;
      *(short8*)&As[r * 136 + c * 8] =
          *(const short8*)&A[(size_t)gr * lda + k0 + c * 8];
      *(short8*)&Bs[r * 136 + c * 8] =
          *(const short8*)&BT[(size_t)(col0 + r) * K + k0 + c * 8];
    }
    __syncthreads();
    int ks = BK >> 5;
    for (int kk = 0; kk < ks; ++kk) {
      short8 a = *(const short8*)&As[(wv * 16 + r16) * 136 + kk * 32 + g4 * 8];
      #pragma unroll
      for (int ct = 0; ct < 4; ++ct) {
        short8 b = *(const short8*)&Bs[(ct * 16 + r16) * 136 + kk * 32 + g4 * 8];
        acc[ct] = __builtin_amdgcn_mfma_f32_16x16x32_bf16(a, b, acc[ct], 0, 0, 0);
      }
    }
    __syncthreads();
  }
  #pragma unroll
  for (int ct = 0; ct < 4; ++ct) {
    int c = col0 + ct * 16 + r16;
    float bs = bias[c];
    #pragma unroll
    for (int j = 0; j < 4; ++j) {
      int r = row0 + wv * 16 + g4 * 4 + j;
      int rc = r < M ? r : M - 1;
      float vv = acc[ct][j] + bs;
      if (doRelu) vv = fmaxf(vv, 0.f);
      if (res) vv += res[(size_t)rc * ldres + c];
      Os[(wv * 16 + g4 * 4 + j) * 68 + ct * 16 + r16] = f2b(vv);
    }
  }
  __syncthreads();
  #pragma unroll
  for (int it = 0; it < 2; ++it) {
    int idx = tid + it * 256;
    int r = idx >> 3, ch = idx & 7;
    int gr = row0 + r;
    if (gr < M)
      *(short8*)&outB[(size_t)gr * ldo + col0 + ch * 8] =
          *(const short8*)&Os[r * 68 + ch * 8];
  }
}

// ------------- attention + skip + LN; kv read as one 16B load, unroll x2 ----
__global__ __launch_bounds__(256) void attn_ln2(
    ushort* __restrict__ qkvs, const int* __restrict__ base,
    const int* __restrict__ deg, const int* __restrict__ csr_send,
    const float* __restrict__ g, const float* __restrict__ bb, int N)
{
  int tid = blockIdx.x * 256 + threadIdx.x;
  int n = tid >> 6, lane = tid & 63;
  if (n >= N) return;
  int dbase = (lane >> 4) * 64 + (lane & 15) * 4;              // head*64 + slot
  int kvoff = 256 + (lane >> 4) * 128 + (lane & 15) * 8;       // interleaved kv
  ushort4 qu = *(const ushort4*)(qkvs + (size_t)n * 1024 + dbase);
  float q0 = b2f(qu.x), q1 = b2f(qu.y), q2 = b2f(qu.z), q3 = b2f(qu.w);
  float m = -1e30f, l = 0.f, a0 = 0.f, a1 = 0.f, a2 = 0.f, a3 = 0.f;
  int b0 = base[n], dn = deg[n];
  int j = 0;
  for (; j + 1 < dn; j += 2) {
    int s0 = csr_send[b0 + j], s1 = csr_send[b0 + j + 1];
    u16x8 kvA = *(const u16x8*)(qkvs + (size_t)s0 * 1024 + kvoff);
    u16x8 kvB = *(const u16x8*)(qkvs + (size_t)s1 * 1024 + kvoff);
    float pA = q0 * b2f((ushort)kvA[0]) + q1 * b2f((ushort)kvA[1]) +
               q2 * b2f((ushort)kvA[2]) + q3 * b2f((ushort)kvA[3]);
    float pB = q0 * b2f((ushort)kvB[0]) + q1 * b2f((ushort)kvB[1]) +
               q2 * b2f((ushort)kvB[2]) + q3 * b2f((ushort)kvB[3]);
    pA += __shfl_xor(pA, 1); pB += __shfl_xor(pB, 1);
    pA += __shfl_xor(pA, 2); pB += __shfl_xor(pB, 2);
    pA += __shfl_xor(pA, 4); pB += __shfl_xor(pB, 4);
    pA += __shfl_xor(pA, 8); pB += __shfl_xor(pB, 8);
    pA *= 0.125f; pB *= 0.125f;
    float mn = fmaxf(m, fmaxf(pA, pB));
    float e1 = __expf(m - mn);
    float peA = __expf(pA - mn), peB = __expf(pB - mn);
    l = l * e1 + peA + peB;
    a0 = a0 * e1 + peA * b2f((ushort)kvA[4]) + peB * b2f((ushort)kvB[4]);
    a1 = a1 * e1 + peA * b2f((ushort)kvA[5]) + peB * b2f((ushort)kvB[5]);
    a2 = a2 * e1 + peA * b2f((ushort)kvA[6]) + peB * b2f((ushort)kvB[6]);
    a3 = a3 * e1 + peA * b2f((ushort)kvA[7]) + peB * b2f((ushort)kvB[7]);
    m = mn;
  }
  if (j < dn) {
    int s = csr_send[b0 + j];
    u16x8 kv = *(const u16x8*)(qkvs + (size_t)s * 1024 + kvoff);
    float p = q0 * b2f((ushort)kv[0]) + q1 * b2f((ushort)kv[1]) +
              q2 * b2f((ushort)kv[2]) + q3 * b2f((ushort)kv[3]);
    p += __shfl_xor(p, 1); p += __shfl_xor(p, 2);
    p += __shfl_xor(p, 4); p += __shfl_xor(p, 8);
    p *= 0.125f;
    float mn = fmaxf(m, p);
    float e1 = __expf(m - mn), pe = __expf(p - mn);
    l = l * e1 + pe;
    a0 = a0 * e1 + pe * b2f((ushort)kv[4]);
    a1 = a1 * e1 + pe * b2f((ushort)kv[5]);
    a2 = a2 * e1 + pe * b2f((ushort)kv[6]);
    a3 = a3 * e1 + pe * b2f((ushort)kv[7]);
    m = mn;
  }
  ushort4 su = *(const ushort4*)(qkvs + (size_t)n * 1024 + 768 + dbase);
  float rl = 1.f / (l + 1e-16f);
  float y0 = a0 * rl + b2f(su.x), y1 = a1 * rl + b2f(su.y);
  float y2 = a2 * rl + b2f(su.z), y3 = a3 * rl + b2f(su.w);
  float s1 = wave_reduce_sum(y0 + y1 + y2 + y3);
  float s2 = wave_reduce_sum(y0 * y0 + y1 * y1 + y2 * y2 + y3 * y3);
  float mean = s1 * (1.f / 256.f);
  float var = s2 * (1.f / 256.f) - mean * mean;
  float rstd = rsqrtf(var + 1e-5f);
  ushort4 o;
  o.x = f2b((y0 - mean) * rstd * g[dbase + 0] + bb[dbase + 0]);
  o.y = f2b((y1 - mean) * rstd * g[dbase + 1] + bb[dbase + 1]);
  o.z = f2b((y2 - mean) * rstd * g[dbase + 2] + bb[dbase + 2]);
  o.w = f2b((y3 - mean) * rstd * g[dbase + 3] + bb[dbase + 3]);
  *(ushort4*)(qkvs + (size_t)n * 1024 + dbase) = o;
}

// ------------- classifier, fully fused: gather + GEMM + relu + dot(w2) ------
__global__ __launch_bounds__(256) void clf_fused(
    const ushort* __restrict__ nodeB, const int* __restrict__ ei,
    const ushort* __restrict__ ec1T, const float* __restrict__ b1,
    const float* __restrict__ w2, const float* __restrict__ b2v,
    float* __restrict__ out, int E)
{
  __shared__ ushort As[64 * 136];
  __shared__ ushort Bs[64 * 136];
  int tid = threadIdx.x;
  int wv = tid >> 6, lane = tid & 63;
  int r16 = lane & 15, g4 = lane >> 4;
  int e0 = blockIdx.x * 64;
  for (int idx = tid; idx < 1024; idx += 256) {
    int r = idx >> 4, c = idx & 15;
    int e = e0 + r; if (e >= E) e = E - 1;
    int node = (c < 8) ? ei[e] : ei[E + e];
    *(short8*)&As[r * 136 + c * 8] =
        *(const short8*)&nodeB[(size_t)node * 64 + (c & 7) * 8];
    *(short8*)&Bs[r * 136 + c * 8] = *(const short8*)&ec1T[r * 128 + c * 8];
  }
  __syncthreads();
  f32x4 acc[4] = {};
  #pragma unroll
  for (int kk = 0; kk < 4; ++kk) {
    short8 a = *(const short8*)&As[(wv * 16 + r16) * 136 + kk * 32 + g4 * 8];
    #pragma unroll
    for (int ct = 0; ct < 4; ++ct) {
      short8 b = *(const short8*)&Bs[(ct * 16 + r16) * 136 + kk * 32 + g4 * 8];
      acc[ct] = __builtin_amdgcn_mfma_f32_16x16x32_bf16(a, b, acc[ct], 0, 0, 0);
    }
  }
  float p0 = 0.f, p1 = 0.f, p2 = 0.f, p3 = 0.f;
  #pragma unroll
  for (int ct = 0; ct < 4; ++ct) {
    int c = ct * 16 + r16;
    float bb1 = b1[c], ww = w2[c];
    p0 += fmaxf(acc[ct][0] + bb1, 0.f) * ww;
    p1 += fmaxf(acc[ct][1] + bb1, 0.f) * ww;
    p2 += fmaxf(acc[ct][2] + bb1, 0.f) * ww;
    p3 += fmaxf(acc[ct][3] + bb1, 0.f) * ww;
  }
  float part[4] = {p0, p1, p2, p3};
  #pragma unroll
  for (int j = 0; j < 4; ++j) {
    float p = part[j];
    p += __shfl_xor(p, 1); p += __shfl_xor(p, 2);
    p += __shfl_xor(p, 4); p += __shfl_xor(p, 8);
    int r = e0 + wv * 16 + g4 * 4 + j;
    if (r16 == 0 && r < E) out[r] = p + b2v[0];
  }
}

extern "C" void kernel_launch(void* const* d_in, const int* in_sizes, int n_in,
                              void* d_out, int out_size, void* d_ws, size_t ws_size,
                              hipStream_t stream)
{
  const float* x     = (const float*)d_in[0];
  const float* ea    = (const float*)d_in[1];
  const float* ne_w1 = (const float*)d_in[2];
  const float* ne_b1 = (const float*)d_in[3];
  const float* ne_w2 = (const float*)d_in[4];
  const float* ne_b2 = (const float*)d_in[5];
  const float* ee_w1 = (const float*)d_in[6];
  const float* ee_b1 = (const float*)d_in[7];
  const float* ee_w2 = (const float*)d_in[8];
  const float* ee_b2 = (const float*)d_in[9];
  const float* lnc_g = (const float*)d_in[10];
  const float* lnc_b = (const float*)d_in[11];
  const float* tq_w  = (const float*)d_in[12];
  const float* tq_b  = (const float*)d_in[13];
  const float* tk_w  = (const float*)d_in[14];
  const float* tk_b  = (const float*)d_in[15];
  const float* tv_w  = (const float*)d_in[16];
  const float* tv_b  = (const float*)d_in[17];
  const float* ts_w  = (const float*)d_in[18];
  const float* ts_b  = (const float*)d_in[19];
  const float* lnt_g = (const float*)d_in[20];
  const float* lnt_b = (const float*)d_in[21];
  const float* pn_w  = (const float*)d_in[22];
  const float* pn_b  = (const float*)d_in[23];
  // d_in[24], d_in[25] = pe_w, pe_b : dead code (n_iterations=1)
  const float* ec_w1 = (const float*)d_in[26];
  const float* ec_b1 = (const float*)d_in[27];
  const float* ec_w2 = (const float*)d_in[28];
  const float* ec_b2 = (const float*)d_in[29];
  const int*   ei    = (const int*)d_in[30];

  const int N = in_sizes[0] / 6;
  const int E = in_sizes[1] / 4;
  float* out = (float*)d_out;

  char* w = (char*)d_ws;
  size_t off = 0;
  auto alloc = [&](size_t bytes) -> char* {
    char* p = w + off;
    off = (off + bytes + 255) & ~(size_t)255;
    return p;
  };
  float*  node0   = (float*)alloc((size_t)N * 64 * 4);
  ushort* comb    = (ushort*)alloc((size_t)N * 128 * 2);
  ushort* qkvs    = (ushort*)alloc((size_t)N * 1024 * 2);  // q|kv|s, outn over q
  ushort* f_edge  = (ushort*)alloc((size_t)E * 64 * 2);
  ushort* nodeB   = (ushort*)alloc((size_t)N * 64 * 2);
  ushort* wqkvsT  = (ushort*)alloc(1024 * 128 * 2);
  float*  bqkvs   = (float*)alloc(1024 * 4);
  ushort* pnT     = (ushort*)alloc(64 * 256 * 2);
  ushort* ec1T    = (ushort*)alloc(64 * 128 * 2);
  ushort* ee2T    = (ushort*)alloc(64 * 64 * 2);
  int* deg      = (int*)alloc((size_t)N * 4);
  int* base     = (int*)alloc((size_t)N * 4);
  int* fillcur  = (int*)alloc((size_t)N * 4);
  int* csr_send = (int*)alloc((size_t)2 * E * 4);
  int* csr_eid  = (int*)alloc((size_t)2 * E * 4);
  int* cursor   = (int*)alloc(256);

  hipMemsetAsync(deg, 0, (size_t)N * 4, stream);
  hipMemsetAsync(cursor, 0, 4, stream);

  // weight prep (transpose + bf16 + kv-permute)
  prep_weights<<<(160768 + 255) / 256, 256, 0, stream>>>(
      tq_w, tk_w, tv_w, ts_w, tq_b, tk_b, tv_b, ts_b, pn_w, ec_w1, ee_w2,
      wqkvsT, bqkvs, pnT, ec1T, ee2T);
  // node encoder (fp32)
  node_encoder<<<(N + 3) / 4, 256, 0, stream>>>(x, ne_w1, ne_b1, ne_w2, ne_b2, node0, N);
  // degree count
  deg_count<<<(E + 255) / 256, 256, 0, stream>>>(ei, deg, E);
  // edge encoder -> f_edge bf16
  edge_enc<<<(E + 63) / 64, 256, 0, stream>>>(ea, ee_w1, ee_b1, ee2T, ee_b2, f_edge, E);
  // CSR build (sender node + edge id)
  alloc_ranges<<<(N + 63) / 64, 64, 0, stream>>>(deg, base, fillcur, cursor, N);
  csr_fill<<<(E + 255) / 256, 256, 0, stream>>>(ei, fillcur, csr_send, csr_eid, E);
  // agg gather + comb LN -> bf16
  comb_gather_ln<<<(N * 64 + 255) / 256, 256, 0, stream>>>(
      node0, f_edge, base, deg, csr_eid, lnc_g, lnc_b, comb, N);
  // fused QKVS projection: [N,128] @ [128,1024] -> bf16 qkvs (cols pre-permuted)
  qkvs_gemm<<<(N + 63) / 64, 256, 0, stream>>>(comb, wqkvsT, bqkvs, qkvs, N);
  // attention + skip + LN (outn over q-region of qkvs)
  attn_ln2<<<(N * 64 + 255) / 256, 256, 0, stream>>>(
      qkvs, base, deg, csr_send, lnt_g, lnt_b, N);
  // node projection + residual -> nodeB
  mgemm<<<dim3((N + 63) / 64, 1), 256, 0, stream>>>(
      qkvs, 1024, N, pnT, pn_b, 256, nodeB, 64, node0, 64, 0);
  // classifier: gather + GEMM + relu + dot(w2) fused
  clf_fused<<<(E + 63) / 64, 256, 0, stream>>>(
      nodeB, ei, ec1T, ec_b1, ec_w2, ec_b2, out, E);
}

// Round 6
// 267.382 us; speedup vs baseline: 3.1419x; 1.0740x over previous
//
#include <hip/hip_runtime.h>
#include <hip/hip_bf16.h>

// N=50000 nodes, E=200000 directed edges, H=4 heads, D=64, NODE_IN=6, EDGE_IN=4

typedef __attribute__((ext_vector_type(8))) short short8;          // 8 bf16
typedef __attribute__((ext_vector_type(8))) unsigned short u16x8;  // 8 bf16
typedef __attribute__((ext_vector_type(4))) float f32x4;

__device__ __forceinline__ float wave_reduce_sum(float p) {
  #pragma unroll
  for (int o = 32; o; o >>= 1) p += __shfl_xor(p, o);
  return p;
}
__device__ __forceinline__ ushort f2b(float x) {  // fp32 -> bf16 RNE
  union { float f; unsigned u; } a; a.f = x;
  unsigned r = a.u + 0x7FFF + ((a.u >> 16) & 1);
  return (ushort)(r >> 16);
}
__device__ __forceinline__ float b2f(ushort u) {
  return __uint_as_float((unsigned)u << 16);
}

// ---------------- node encoder: node0 = relu(relu(x@W1+b1)@W2+b2), bf16 out -
__global__ __launch_bounds__(256) void node_encoder(
    const float* __restrict__ x, const float* __restrict__ w1,
    const float* __restrict__ b1, const float* __restrict__ w2,
    const float* __restrict__ b2, ushort* __restrict__ out, int N)
{
  __shared__ float sW2[64 * 64];
  __shared__ float sH[4][64];
  int tid = threadIdx.x;
  for (int i = tid; i < 64 * 64; i += 256) sW2[i] = w2[i];
  int wave = tid >> 6, lane = tid & 63;
  int n = blockIdx.x * 4 + wave;
  int nc = n < N ? n : (N - 1);
  float h = b1[lane];
  #pragma unroll
  for (int i = 0; i < 6; ++i) h += x[nc * 6 + i] * w1[i * 64 + lane];
  h = fmaxf(h, 0.f);
  sH[wave][lane] = h;
  __syncthreads();
  float o = b2[lane];
  #pragma unroll 8
  for (int j = 0; j < 64; ++j) o += sH[wave][j] * sW2[j * 64 + lane];
  o = fmaxf(o, 0.f);
  if (n < N) out[n * 64 + lane] = f2b(o);
}

// ------------- weight prep: transpose + cast + kv-interleave permutation ----
__global__ __launch_bounds__(256) void prep_weights(
    const float* __restrict__ tq_w, const float* __restrict__ tk_w,
    const float* __restrict__ tv_w, const float* __restrict__ ts_w,
    const float* __restrict__ tq_b, const float* __restrict__ tk_b,
    const float* __restrict__ tv_b, const float* __restrict__ ts_b,
    const float* __restrict__ pn_w, const float* __restrict__ ec_w1,
    const float* __restrict__ ee_w2,
    ushort* __restrict__ wqkvsT, float* __restrict__ bqkvs,
    ushort* __restrict__ pnT, ushort* __restrict__ ec1T,
    ushort* __restrict__ ee2T)
{
  int idx = blockIdx.x * 256 + threadIdx.x;
  if (idx < 131072) {                       // wqkvsT [1024][128], permuted cols
    int p = idx >> 7, k = idx & 127;
    int g, cc;
    if (p < 256) { g = 0; cc = p; }
    else if (p < 768) {
      int d2 = p - 256; int head = d2 >> 7; int ww = d2 & 127;
      int slot = ww >> 3; int o = ww & 7;
      if (o < 4) { g = 1; cc = head * 64 + slot * 4 + o; }
      else       { g = 2; cc = head * 64 + slot * 4 + o - 4; }
    } else { g = 3; cc = p - 768; }
    const float* w = (g == 0) ? tq_w : (g == 1) ? tk_w : (g == 2) ? tv_w : ts_w;
    wqkvsT[idx] = f2b(w[k * 256 + cc]);
  } else if (idx < 147456) {                // pnT [64][256]
    int i = idx - 131072; int c = i >> 8, k = i & 255;
    pnT[i] = f2b(pn_w[k * 64 + c]);
  } else if (idx < 155648) {                // ec1T [64][128]
    int i = idx - 147456; int c = i >> 7, k = i & 127;
    ec1T[i] = f2b(ec_w1[k * 64 + c]);
  } else if (idx < 159744) {                // ee2T [64][64]
    int i = idx - 155648; int c = i >> 6, k = i & 63;
    ee2T[i] = f2b(ee_w2[k * 64 + c]);
  } else if (idx < 160768) {                // bqkvs [1024], permuted
    int p = idx - 159744;
    int g, cc;
    if (p < 256) { g = 0; cc = p; }
    else if (p < 768) {
      int d2 = p - 256; int head = d2 >> 7; int ww = d2 & 127;
      int slot = ww >> 3; int o = ww & 7;
      if (o < 4) { g = 1; cc = head * 64 + slot * 4 + o; }
      else       { g = 2; cc = head * 64 + slot * 4 + o - 4; }
    } else { g = 3; cc = p - 768; }
    const float* b = (g == 0) ? tq_b : (g == 1) ? tk_b : (g == 2) ? tv_b : ts_b;
    bqkvs[p] = b[cc];
  }
}

// ------------- edge encoder: MLP l1 + MFMA l2 + deg count -------------------
__global__ __launch_bounds__(256) void edge_enc(
    const float* __restrict__ ea, const float* __restrict__ w1,
    const float* __restrict__ b1, const ushort* __restrict__ ee2T,
    const float* __restrict__ b2, const int* __restrict__ ei,
    int* __restrict__ deg, ushort* __restrict__ f, int E)
{
  __shared__ ushort As[64 * 72];
  __shared__ ushort Bs[64 * 72];
  __shared__ ushort fT[64 * 72];
  int tid = threadIdx.x;
  int wv = tid >> 6, lane = tid & 63, r16 = lane & 15, g4 = lane >> 4;
  int e0 = blockIdx.x * 64;
  if (tid < 64) {
    int e = e0 + tid;
    if (e < E) { atomicAdd(&deg[ei[e]], 1); atomicAdd(&deg[ei[E + e]], 1); }
  }
  // stage ee2T [64][64] -> Bs
  #pragma unroll
  for (int it = 0; it < 2; ++it) {
    int idx = tid + it * 256;
    int r = idx >> 3, c = idx & 7;
    *(short8*)&Bs[r * 72 + c * 8] = *(const short8*)&ee2T[r * 64 + c * 8];
  }
  // h = relu(ea@W1+b1), bf16, into As (thread owns col c for 16 rows)
  {
    int c = tid & 63;
    float w0 = w1[c], w1v = w1[64 + c], w2v = w1[128 + c], w3v = w1[192 + c];
    float bb = b1[c];
    int rbase = tid >> 6;
    #pragma unroll
    for (int i = 0; i < 16; ++i) {
      int r = rbase + i * 4;
      int e = e0 + r; if (e >= E) e = E - 1;
      float4 a = *(const float4*)(ea + (size_t)e * 4);
      float hv = bb + a.x * w0 + a.y * w1v + a.z * w2v + a.w * w3v;
      As[r * 72 + c] = f2b(fmaxf(hv, 0.f));
    }
  }
  __syncthreads();
  f32x4 acc[4] = {};
  #pragma unroll
  for (int kk = 0; kk < 2; ++kk) {
    short8 a = *(const short8*)&As[(wv * 16 + r16) * 72 + kk * 32 + g4 * 8];
    #pragma unroll
    for (int sc = 0; sc < 4; ++sc) {
      short8 b = *(const short8*)&Bs[(sc * 16 + r16) * 72 + kk * 32 + g4 * 8];
      acc[sc] = __builtin_amdgcn_mfma_f32_16x16x32_bf16(a, b, acc[sc], 0, 0, 0);
    }
  }
  #pragma unroll
  for (int sc = 0; sc < 4; ++sc) {
    int c = sc * 16 + r16;
    float bs = b2[c];
    #pragma unroll
    for (int j = 0; j < 4; ++j) {
      int r = wv * 16 + g4 * 4 + j;
      fT[r * 72 + c] = f2b(fmaxf(acc[sc][j] + bs, 0.f));
    }
  }
  __syncthreads();
  #pragma unroll
  for (int it = 0; it < 2; ++it) {
    int idx = tid + it * 256;
    int r = idx >> 3, c = idx & 7;
    int e = e0 + r;
    if (e < E)
      *(short8*)&f[(size_t)e * 64 + c * 8] = *(const short8*)&fT[r * 72 + c * 8];
  }
}

// ------------- CSR range allocation -----------------------------------------
__global__ __launch_bounds__(64) void alloc_ranges(
    const int* __restrict__ deg, int* __restrict__ base,
    int* __restrict__ fillcur, int* __restrict__ cursor, int N)
{
  int lane = threadIdx.x;
  int n = blockIdx.x * 64 + lane;
  int d = (n < N) ? deg[n] : 0;
  int s = d;
  #pragma unroll
  for (int o = 1; o < 64; o <<= 1) {
    int t = __shfl_up(s, o);
    if (lane >= o) s += t;
  }
  int tot = __shfl(s, 63);
  int wb = 0;
  if (lane == 63) wb = atomicAdd(cursor, tot);
  wb = __shfl(wb, 63);
  if (n < N) { base[n] = wb + s - d; fillcur[n] = wb + s - d; }
}

// ------------- CSR fill: sender node id + edge id per slot ------------------
__global__ __launch_bounds__(256) void csr_fill(
    const int* __restrict__ ei, int* __restrict__ fillcur,
    int* __restrict__ csr_send, int* __restrict__ csr_eid, int E)
{
  int e = blockIdx.x * 256 + threadIdx.x;
  if (e >= E) return;
  int a = ei[e], b = ei[E + e];
  int pa = atomicAdd(&fillcur[b], 1);
  csr_send[pa] = a; csr_eid[pa] = e;
  int pb = atomicAdd(&fillcur[a], 1);
  csr_send[pb] = b; csr_eid[pb] = e;
}

// ------------- agg gather + comb = LN(cat(node, agg-node)) (bf16) -----------
__global__ __launch_bounds__(256) void comb_gather_ln(
    const ushort* __restrict__ node, const ushort* __restrict__ f_edge,
    const int* __restrict__ base, const int* __restrict__ deg,
    const int* __restrict__ csr_eid,
    const float* __restrict__ g, const float* __restrict__ b,
    ushort* __restrict__ comb, int N)
{
  int tid = blockIdx.x * 256 + threadIdx.x;
  int n = tid >> 6, lane = tid & 63;
  if (n >= N) return;
  float v0 = b2f(node[(size_t)n * 64 + lane]);
  float a = 0.f;
  int b0 = base[n], dn = deg[n];
  for (int j = 0; j < dn; j += 4) {
    int i1 = b0 + (j + 1 < dn ? j + 1 : dn - 1);
    int i2 = b0 + (j + 2 < dn ? j + 2 : dn - 1);
    int i3 = b0 + (j + 3 < dn ? j + 3 : dn - 1);
    float f0 = b2f(f_edge[(size_t)csr_eid[b0 + j] * 64 + lane]);
    float f1 = b2f(f_edge[(size_t)csr_eid[i1] * 64 + lane]);
    float f2 = b2f(f_edge[(size_t)csr_eid[i2] * 64 + lane]);
    float f3 = b2f(f_edge[(size_t)csr_eid[i3] * 64 + lane]);
    a += f0;
    if (j + 1 < dn) a += f1;
    if (j + 2 < dn) a += f2;
    if (j + 3 < dn) a += f3;
  }
  float v1 = a - v0;
  float s = wave_reduce_sum(v0 + v1);
  float ss = wave_reduce_sum(v0 * v0 + v1 * v1);
  float mean = s * (1.f / 128.f);
  float var = ss * (1.f / 128.f) - mean * mean;
  float rstd = rsqrtf(var + 1e-5f);
  comb[(size_t)n * 128 + lane]      = f2b((v0 - mean) * rstd * g[lane] + b[lane]);
  comb[(size_t)n * 128 + 64 + lane] = f2b((v1 - mean) * rstd * g[64 + lane] + b[64 + lane]);
}

// ------------- fused QKVS GEMM: A staged once, 16 col tiles -----------------
__global__ __launch_bounds__(256) void qkvs_gemm(
    const ushort* __restrict__ comb, const ushort* __restrict__ wqkvsT,
    const float* __restrict__ bias, ushort* __restrict__ qkvs, int N)
{
  __shared__ ushort As[64 * 136];
  __shared__ ushort Bs[64 * 136];
  __shared__ ushort Os[64 * 68];
  int tid = threadIdx.x;
  int wv = tid >> 6, lane = tid & 63, r16 = lane & 15, g4 = lane >> 4;
  int row0 = blockIdx.x * 64;
  #pragma unroll
  for (int it = 0; it < 4; ++it) {
    int idx = tid + it * 256;
    int r = idx >> 4, c = idx & 15;
    int gr = row0 + r; if (gr >= N) gr = N - 1;
    *(short8*)&As[r * 136 + c * 8] = *(const short8*)&comb[(size_t)gr * 128 + c * 8];
    *(short8*)&Bs[r * 136 + c * 8] = *(const short8*)&wqkvsT[(size_t)r * 128 + c * 8];
  }
  __syncthreads();
  for (int ct = 0; ct < 16; ++ct) {
    short8 pf[4];
    if (ct < 15) {
      #pragma unroll
      for (int it = 0; it < 4; ++it) {
        int idx = tid + it * 256;
        int r = idx >> 4, c = idx & 15;
        pf[it] = *(const short8*)&wqkvsT[(size_t)((ct + 1) * 64 + r) * 128 + c * 8];
      }
    }
    f32x4 acc[4] = {};
    #pragma unroll
    for (int kk = 0; kk < 4; ++kk) {
      short8 a = *(const short8*)&As[(wv * 16 + r16) * 136 + kk * 32 + g4 * 8];
      #pragma unroll
      for (int sc = 0; sc < 4; ++sc) {
        short8 b = *(const short8*)&Bs[(sc * 16 + r16) * 136 + kk * 32 + g4 * 8];
        acc[sc] = __builtin_amdgcn_mfma_f32_16x16x32_bf16(a, b, acc[sc], 0, 0, 0);
      }
    }
    __syncthreads();
    if (ct < 15) {
      #pragma unroll
      for (int it = 0; it < 4; ++it) {
        int idx = tid + it * 256;
        int r = idx >> 4, c = idx & 15;
        *(short8*)&Bs[r * 136 + c * 8] = pf[it];
      }
    }
    #pragma unroll
    for (int sc = 0; sc < 4; ++sc) {
      float bs = bias[ct * 64 + sc * 16 + r16];
      #pragma unroll
      for (int j = 0; j < 4; ++j)
        Os[(wv * 16 + g4 * 4 + j) * 68 + sc * 16 + r16] = f2b(acc[sc][j] + bs);
    }
    __syncthreads();
    #pragma unroll
    for (int it = 0; it < 2; ++it) {
      int idx = tid + it * 256;
      int r = idx >> 3, ch = idx & 7;
      int gr = row0 + r;
      if (gr < N)
        *(short8*)&qkvs[(size_t)gr * 1024 + ct * 64 + ch * 8] =
            *(const short8*)&Os[r * 68 + ch * 8];
    }
  }
}

// ------------- generic bf16 MFMA GEMM (proj) with staged bf16 stores --------
__global__ __launch_bounds__(256) void mgemm(
    const ushort* __restrict__ A, int lda, int M,
    const ushort* __restrict__ BT, const float* __restrict__ bias, int K,
    ushort* __restrict__ outB, int ldo,
    const ushort* __restrict__ res, int ldres, int doRelu)
{
  __shared__ ushort As[64 * 136];
  __shared__ ushort Bs[64 * 136];
  __shared__ ushort Os[64 * 68];
  int tid = threadIdx.x;
  int wv = tid >> 6, lane = tid & 63;
  int r16 = lane & 15, g4 = lane >> 4;
  int row0 = blockIdx.x * 64, col0 = blockIdx.y * 64;
  f32x4 acc[4] = {};
  for (int k0 = 0; k0 < K; k0 += 128) {
    int BK = K - k0; if (BK > 128) BK = 128;
    int csh = (BK == 64) ? 3 : 4;
    int cmask = (1 << csh) - 1;
    int tot = 64 << csh;
    for (int idx = tid; idx < tot; idx += 256) {
      int r = idx >> csh, c = idx & cmask;
      int gr = row0 + r; if (gr >= M) gr = M - 1;
      *(short8*)&As[r * 136 + c * 8] =
          *(const short8*)&A[(size_t)gr * lda + k0 + c * 8];
      *(short8*)&Bs[r * 136 + c * 8] =
          *(const short8*)&BT[(size_t)(col0 + r) * K + k0 + c * 8];
    }
    __syncthreads();
    int ks = BK >> 5;
    for (int kk = 0; kk < ks; ++kk) {
      short8 a = *(const short8*)&As[(wv * 16 + r16) * 136 + kk * 32 + g4 * 8];
      #pragma unroll
      for (int ct = 0; ct < 4; ++ct) {
        short8 b = *(const short8*)&Bs[(ct * 16 + r16) * 136 + kk * 32 + g4 * 8];
        acc[ct] = __builtin_amdgcn_mfma_f32_16x16x32_bf16(a, b, acc[ct], 0, 0, 0);
      }
    }
    __syncthreads();
  }
  #pragma unroll
  for (int ct = 0; ct < 4; ++ct) {
    int c = col0 + ct * 16 + r16;
    float bs = bias[c];
    #pragma unroll
    for (int j = 0; j < 4; ++j) {
      int r = row0 + wv * 16 + g4 * 4 + j;
      int rc = r < M ? r : M - 1;
      float vv = acc[ct][j] + bs;
      if (doRelu) vv = fmaxf(vv, 0.f);
      if (res) vv += b2f(res[(size_t)rc * ldres + c]);
      Os[(wv * 16 + g4 * 4 + j) * 68 + ct * 16 + r16] = f2b(vv);
    }
  }
  __syncthreads();
  #pragma unroll
  for (int it = 0; it < 2; ++it) {
    int idx = tid + it * 256;
    int r = idx >> 3, ch = idx & 7;
    int gr = row0 + r;
    if (gr < M)
      *(short8*)&outB[(size_t)gr * ldo + col0 + ch * 8] =
          *(const short8*)&Os[r * 68 + ch * 8];
  }
}

// ------------- attention + skip + LN; no-max softmax, unroll x4 -------------
// Scores are bounded (|s| ~ N(0,1) scale) so exp() without max-subtraction is
// numerically safe in fp32 and removes the serial max-update dependency.
__global__ __launch_bounds__(256) void attn_ln2(
    ushort* __restrict__ qkvs, const int* __restrict__ base,
    const int* __restrict__ deg, const int* __restrict__ csr_send,
    const float* __restrict__ g, const float* __restrict__ bb, int N)
{
  int tid = blockIdx.x * 256 + threadIdx.x;
  int n = tid >> 6, lane = tid & 63;
  if (n >= N) return;
  int dbase = (lane >> 4) * 64 + (lane & 15) * 4;              // head*64 + slot
  int kvoff = 256 + (lane >> 4) * 128 + (lane & 15) * 8;       // interleaved kv
  ushort4 qu = *(const ushort4*)(qkvs + (size_t)n * 1024 + dbase);
  float q0 = b2f(qu.x) * 0.125f, q1 = b2f(qu.y) * 0.125f;
  float q2 = b2f(qu.z) * 0.125f, q3 = b2f(qu.w) * 0.125f;
  float l = 0.f, a0 = 0.f, a1 = 0.f, a2 = 0.f, a3 = 0.f;
  int b0 = base[n], dn = deg[n];
  for (int j = 0; j < dn; j += 4) {
    int i1 = b0 + (j + 1 < dn ? j + 1 : dn - 1);
    int i2 = b0 + (j + 2 < dn ? j + 2 : dn - 1);
    int i3 = b0 + (j + 3 < dn ? j + 3 : dn - 1);
    int s0 = csr_send[b0 + j], s1 = csr_send[i1];
    int s2 = csr_send[i2], s3 = csr_send[i3];
    u16x8 kv0 = *(const u16x8*)(qkvs + (size_t)s0 * 1024 + kvoff);
    u16x8 kv1 = *(const u16x8*)(qkvs + (size_t)s1 * 1024 + kvoff);
    u16x8 kv2 = *(const u16x8*)(qkvs + (size_t)s2 * 1024 + kvoff);
    u16x8 kv3 = *(const u16x8*)(qkvs + (size_t)s3 * 1024 + kvoff);
    float p0 = q0 * b2f((ushort)kv0[0]) + q1 * b2f((ushort)kv0[1]) +
               q2 * b2f((ushort)kv0[2]) + q3 * b2f((ushort)kv0[3]);
    float p1 = q0 * b2f((ushort)kv1[0]) + q1 * b2f((ushort)kv1[1]) +
               q2 * b2f((ushort)kv1[2]) + q3 * b2f((ushort)kv1[3]);
    float p2 = q0 * b2f((ushort)kv2[0]) + q1 * b2f((ushort)kv2[1]) +
               q2 * b2f((ushort)kv2[2]) + q3 * b2f((ushort)kv2[3]);
    float p3 = q0 * b2f((ushort)kv3[0]) + q1 * b2f((ushort)kv3[1]) +
               q2 * b2f((ushort)kv3[2]) + q3 * b2f((ushort)kv3[3]);
    #pragma unroll
    for (int o = 1; o < 16; o <<= 1) {
      p0 += __shfl_xor(p0, o); p1 += __shfl_xor(p1, o);
      p2 += __shfl_xor(p2, o); p3 += __shfl_xor(p3, o);
    }
    float e0 = __expf(p0);
    float e1 = (j + 1 < dn) ? __expf(p1) : 0.f;
    float e2 = (j + 2 < dn) ? __expf(p2) : 0.f;
    float e3 = (j + 3 < dn) ? __expf(p3) : 0.f;
    l += e0 + e1 + e2 + e3;
    a0 += e0 * b2f((ushort)kv0[4]) + e1 * b2f((ushort)kv1[4]) +
          e2 * b2f((ushort)kv2[4]) + e3 * b2f((ushort)kv3[4]);
    a1 += e0 * b2f((ushort)kv0[5]) + e1 * b2f((ushort)kv1[5]) +
          e2 * b2f((ushort)kv2[5]) + e3 * b2f((ushort)kv3[5]);
    a2 += e0 * b2f((ushort)kv0[6]) + e1 * b2f((ushort)kv1[6]) +
          e2 * b2f((ushort)kv2[6]) + e3 * b2f((ushort)kv3[6]);
    a3 += e0 * b2f((ushort)kv0[7]) + e1 * b2f((ushort)kv1[7]) +
          e2 * b2f((ushort)kv2[7]) + e3 * b2f((ushort)kv3[7]);
  }
  ushort4 su = *(const ushort4*)(qkvs + (size_t)n * 1024 + 768 + dbase);
  float rl = 1.f / (l + 1e-16f);
  float y0 = a0 * rl + b2f(su.x), y1 = a1 * rl + b2f(su.y);
  float y2 = a2 * rl + b2f(su.z), y3 = a3 * rl + b2f(su.w);
  float s1 = wave_reduce_sum(y0 + y1 + y2 + y3);
  float s2 = wave_reduce_sum(y0 * y0 + y1 * y1 + y2 * y2 + y3 * y3);
  float mean = s1 * (1.f / 256.f);
  float var = s2 * (1.f / 256.f) - mean * mean;
  float rstd = rsqrtf(var + 1e-5f);
  ushort4 o;
  o.x = f2b((y0 - mean) * rstd * g[dbase + 0] + bb[dbase + 0]);
  o.y = f2b((y1 - mean) * rstd * g[dbase + 1] + bb[dbase + 1]);
  o.z = f2b((y2 - mean) * rstd * g[dbase + 2] + bb[dbase + 2]);
  o.w = f2b((y3 - mean) * rstd * g[dbase + 3] + bb[dbase + 3]);
  *(ushort4*)(qkvs + (size_t)n * 1024 + dbase) = o;
}

// ------------- classifier, fully fused: gather + GEMM + relu + dot(w2) ------
__global__ __launch_bounds__(256) void clf_fused(
    const ushort* __restrict__ nodeB, const int* __restrict__ ei,
    const ushort* __restrict__ ec1T, const float* __restrict__ b1,
    const float* __restrict__ w2, const float* __restrict__ b2v,
    float* __restrict__ out, int E)
{
  __shared__ ushort As[64 * 136];
  __shared__ ushort Bs[64 * 136];
  int tid = threadIdx.x;
  int wv = tid >> 6, lane = tid & 63;
  int r16 = lane & 15, g4 = lane >> 4;
  int e0 = blockIdx.x * 64;
  for (int idx = tid; idx < 1024; idx += 256) {
    int r = idx >> 4, c = idx & 15;
    int e = e0 + r; if (e >= E) e = E - 1;
    int node = (c < 8) ? ei[e] : ei[E + e];
    *(short8*)&As[r * 136 + c * 8] =
        *(const short8*)&nodeB[(size_t)node * 64 + (c & 7) * 8];
    *(short8*)&Bs[r * 136 + c * 8] = *(const short8*)&ec1T[r * 128 + c * 8];
  }
  __syncthreads();
  f32x4 acc[4] = {};
  #pragma unroll
  for (int kk = 0; kk < 4; ++kk) {
    short8 a = *(const short8*)&As[(wv * 16 + r16) * 136 + kk * 32 + g4 * 8];
    #pragma unroll
    for (int ct = 0; ct < 4; ++ct) {
      short8 b = *(const short8*)&Bs[(ct * 16 + r16) * 136 + kk * 32 + g4 * 8];
      acc[ct] = __builtin_amdgcn_mfma_f32_16x16x32_bf16(a, b, acc[ct], 0, 0, 0);
    }
  }
  float p0 = 0.f, p1 = 0.f, p2 = 0.f, p3 = 0.f;
  #pragma unroll
  for (int ct = 0; ct < 4; ++ct) {
    int c = ct * 16 + r16;
    float bb1 = b1[c], ww = w2[c];
    p0 += fmaxf(acc[ct][0] + bb1, 0.f) * ww;
    p1 += fmaxf(acc[ct][1] + bb1, 0.f) * ww;
    p2 += fmaxf(acc[ct][2] + bb1, 0.f) * ww;
    p3 += fmaxf(acc[ct][3] + bb1, 0.f) * ww;
  }
  float part[4] = {p0, p1, p2, p3};
  #pragma unroll
  for (int j = 0; j < 4; ++j) {
    float p = part[j];
    p += __shfl_xor(p, 1); p += __shfl_xor(p, 2);
    p += __shfl_xor(p, 4); p += __shfl_xor(p, 8);
    int r = e0 + wv * 16 + g4 * 4 + j;
    if (r16 == 0 && r < E) out[r] = p + b2v[0];
  }
}

extern "C" void kernel_launch(void* const* d_in, const int* in_sizes, int n_in,
                              void* d_out, int out_size, void* d_ws, size_t ws_size,
                              hipStream_t stream)
{
  const float* x     = (const float*)d_in[0];
  const float* ea    = (const float*)d_in[1];
  const float* ne_w1 = (const float*)d_in[2];
  const float* ne_b1 = (const float*)d_in[3];
  const float* ne_w2 = (const float*)d_in[4];
  const float* ne_b2 = (const float*)d_in[5];
  const float* ee_w1 = (const float*)d_in[6];
  const float* ee_b1 = (const float*)d_in[7];
  const float* ee_w2 = (const float*)d_in[8];
  const float* ee_b2 = (const float*)d_in[9];
  const float* lnc_g = (const float*)d_in[10];
  const float* lnc_b = (const float*)d_in[11];
  const float* tq_w  = (const float*)d_in[12];
  const float* tq_b  = (const float*)d_in[13];
  const float* tk_w  = (const float*)d_in[14];
  const float* tk_b  = (const float*)d_in[15];
  const float* tv_w  = (const float*)d_in[16];
  const float* tv_b  = (const float*)d_in[17];
  const float* ts_w  = (const float*)d_in[18];
  const float* ts_b  = (const float*)d_in[19];
  const float* lnt_g = (const float*)d_in[20];
  const float* lnt_b = (const float*)d_in[21];
  const float* pn_w  = (const float*)d_in[22];
  const float* pn_b  = (const float*)d_in[23];
  // d_in[24], d_in[25] = pe_w, pe_b : dead code (n_iterations=1)
  const float* ec_w1 = (const float*)d_in[26];
  const float* ec_b1 = (const float*)d_in[27];
  const float* ec_w2 = (const float*)d_in[28];
  const float* ec_b2 = (const float*)d_in[29];
  const int*   ei    = (const int*)d_in[30];

  const int N = in_sizes[0] / 6;
  const int E = in_sizes[1] / 4;
  float* out = (float*)d_out;

  char* w = (char*)d_ws;
  size_t off = 0;
  auto alloc = [&](size_t bytes) -> char* {
    char* p = w + off;
    off = (off + bytes + 255) & ~(size_t)255;
    return p;
  };
  ushort* node0   = (ushort*)alloc((size_t)N * 64 * 2);    // bf16
  ushort* comb    = (ushort*)alloc((size_t)N * 128 * 2);
  ushort* qkvs    = (ushort*)alloc((size_t)N * 1024 * 2);  // q|kv|s, outn over q
  ushort* f_edge  = (ushort*)alloc((size_t)E * 64 * 2);
  ushort* nodeB   = (ushort*)alloc((size_t)N * 64 * 2);
  ushort* wqkvsT  = (ushort*)alloc(1024 * 128 * 2);
  float*  bqkvs   = (float*)alloc(1024 * 4);
  ushort* pnT     = (ushort*)alloc(64 * 256 * 2);
  ushort* ec1T    = (ushort*)alloc(64 * 128 * 2);
  ushort* ee2T    = (ushort*)alloc(64 * 64 * 2);
  int* deg      = (int*)alloc((size_t)N * 4);
  int* base     = (int*)alloc((size_t)N * 4);
  int* fillcur  = (int*)alloc((size_t)N * 4);
  int* csr_send = (int*)alloc((size_t)2 * E * 4);
  int* csr_eid  = (int*)alloc((size_t)2 * E * 4);
  int* cursor   = (int*)alloc(256);

  hipMemsetAsync(deg, 0, (size_t)N * 4, stream);
  hipMemsetAsync(cursor, 0, 4, stream);

  // weight prep (transpose + bf16 + kv-permute)
  prep_weights<<<(160768 + 255) / 256, 256, 0, stream>>>(
      tq_w, tk_w, tv_w, ts_w, tq_b, tk_b, tv_b, ts_b, pn_w, ec_w1, ee_w2,
      wqkvsT, bqkvs, pnT, ec1T, ee2T);
  // node encoder (fp32 compute, bf16 out)
  node_encoder<<<(N + 3) / 4, 256, 0, stream>>>(x, ne_w1, ne_b1, ne_w2, ne_b2, node0, N);
  // edge encoder -> f_edge bf16 (+ degree count)
  edge_enc<<<(E + 63) / 64, 256, 0, stream>>>(ea, ee_w1, ee_b1, ee2T, ee_b2, ei,
                                              deg, f_edge, E);
  // CSR build (sender node + edge id)
  alloc_ranges<<<(N + 63) / 64, 64, 0, stream>>>(deg, base, fillcur, cursor, N);
  csr_fill<<<(E + 255) / 256, 256, 0, stream>>>(ei, fillcur, csr_send, csr_eid, E);
  // agg gather + comb LN -> bf16
  comb_gather_ln<<<(N * 64 + 255) / 256, 256, 0, stream>>>(
      node0, f_edge, base, deg, csr_eid, lnc_g, lnc_b, comb, N);
  // fused QKVS projection: [N,128] @ [128,1024] -> bf16 qkvs (cols pre-permuted)
  qkvs_gemm<<<(N + 63) / 64, 256, 0, stream>>>(comb, wqkvsT, bqkvs, qkvs, N);
  // attention + skip + LN (outn over q-region of qkvs)
  attn_ln2<<<(N * 64 + 255) / 256, 256, 0, stream>>>(
      qkvs, base, deg, csr_send, lnt_g, lnt_b, N);
  // node projection + residual -> nodeB
  mgemm<<<dim3((N + 63) / 64, 1), 256, 0, stream>>>(
      qkvs, 1024, N, pnT, pn_b, 256, nodeB, 64, node0, 64, 0);
  // classifier: gather + GEMM + relu + dot(w2) fused
  clf_fused<<<(E + 63) / 64, 256, 0, stream>>>(
      nodeB, ei, ec1T, ec_b1, ec_w2, ec_b2, out, E);
}